// Round 1
// baseline (701.909 us; speedup 1.0000x reference)
//
#include <hip/hip_runtime.h>
#include <math.h>

#define N 512
#define CS 384
#define CP 128
#define CH 16
#define NH 12
#define NN (N*N)
#define DCAT 2112
#define INFV 100000.0f

__device__ __constant__ float SC_QK = 0.14433756729740643f; // sqrt(1/48)
#define SC_B  0.57735026918962576f  // sqrt(1/3)
#define HW_SC 0.13608276348795434f  // sqrt(1/54)

// ---------------- generic row-tiled GEMM: Y[N x KOUT] = X[N x KIN] @ W + b ----------------
__global__ void gemm_rows(const float* __restrict__ X, const float* __restrict__ W,
                          const float* __restrict__ bias, const float* __restrict__ resid,
                          float* __restrict__ Y, int KIN, int KOUT, int relu)
{
    extern __shared__ float xs[];
    const int i0 = blockIdx.x * 4;
    const int t = threadIdx.x;
    for (int idx = t; idx < 4 * KIN; idx += 192)
        xs[idx] = X[(size_t)i0 * KIN + idx];
    __syncthreads();
    int col = blockIdx.y * 192 + t;
    if (col >= KOUT) return;
    float a0 = 0.f, a1 = 0.f, a2 = 0.f, a3 = 0.f;
    for (int k = 0; k < KIN; ++k) {
        float wv = W[(size_t)k * KOUT + col];
        a0 += xs[k] * wv;
        a1 += xs[KIN + k] * wv;
        a2 += xs[2 * KIN + k] * wv;
        a3 += xs[3 * KIN + k] * wv;
    }
    float bv = bias[col];
    float o0 = a0 + bv, o1 = a1 + bv, o2 = a2 + bv, o3 = a3 + bv;
    if (resid) {
        o0 += resid[(size_t)(i0 + 0) * KOUT + col];
        o1 += resid[(size_t)(i0 + 1) * KOUT + col];
        o2 += resid[(size_t)(i0 + 2) * KOUT + col];
        o3 += resid[(size_t)(i0 + 3) * KOUT + col];
    }
    if (relu) {
        o0 = fmaxf(o0, 0.f); o1 = fmaxf(o1, 0.f);
        o2 = fmaxf(o2, 0.f); o3 = fmaxf(o3, 0.f);
    }
    Y[(size_t)(i0 + 0) * KOUT + col] = o0;
    Y[(size_t)(i0 + 1) * KOUT + col] = o1;
    Y[(size_t)(i0 + 2) * KOUT + col] = o2;
    Y[(size_t)(i0 + 3) * KOUT + col] = o3;
}

// ---------------- rotate points in place: v <- R v + t ----------------
__global__ void rotate_pts(float* __restrict__ pts, const float* __restrict__ rot,
                           const float* __restrict__ trans, int P)
{
    int gid = blockIdx.x * 256 + threadIdx.x;
    if (gid >= N * P) return;
    int n = gid / P;
    float* v = pts + (size_t)gid * 3;
    float x = v[0], y = v[1], z = v[2];
    const float* R = rot + n * 9;
    const float* T = trans + n * 3;
    v[0] = R[0] * x + R[1] * y + R[2] * z + T[0];
    v[1] = R[3] * x + R[4] * y + R[5] * z + T[1];
    v[2] = R[6] * x + R[7] * y + R[8] * z + T[2];
}

// ---------------- bias = sqrt(1/3) * (p @ w_b + b_b), stored transposed (h, i*N+j) ----------------
__global__ void bias_kernel(const float* __restrict__ p, const float* __restrict__ w_b,
                            const float* __restrict__ b_b, float* __restrict__ attn)
{
    __shared__ float Ps[32 * 130];
    __shared__ float Wb[CP * NH];
    const int t = threadIdx.x;
    const int m0 = blockIdx.x * 32;
    for (int idx = t; idx < 4096; idx += 256) {
        int jj = idx >> 7, c = idx & 127;
        Ps[jj * 130 + c] = p[(size_t)m0 * 128 + idx];
    }
    for (int idx = t; idx < CP * NH; idx += 256) Wb[idx] = w_b[idx];
    __syncthreads();
    for (int o = t; o < 384; o += 256) {
        int r = o & 31, h = o >> 5;
        float acc = 0.f;
        for (int c = 0; c < 128; ++c) acc += Ps[r * 130 + c] * Wb[c * 12 + h];
        attn[(size_t)h * NN + m0 + r] = SC_B * (acc + b_b[h]);
    }
}

// ---------------- logits (qk + bias + point term + mask) + softmax, in place ----------------
__global__ void attn_kernel(const float* __restrict__ q, const float* __restrict__ kv,
                            const float* __restrict__ qp, const float* __restrict__ kvp,
                            const float* __restrict__ head_w, const float* __restrict__ mask,
                            float* __restrict__ attn)
{
    __shared__ float qv[16], qpv[12], row[512], red[4];
    __shared__ float sh_hw;
    const int i = blockIdx.x, h = blockIdx.y, t = threadIdx.x;
    if (t < 16) qv[t] = q[i * 192 + h * 16 + t];
    if (t < 12) qpv[t] = qp[i * 144 + h * 12 + t];
    if (t == 0) sh_hw = 0.5f * HW_SC * log1pf(expf(head_w[h]));
    __syncthreads();
    float mi = mask[i];
    float* arow = attn + ((size_t)h * N + i) * N;
    for (int j = t; j < N; j += 256) {
        const float* kr = kv + j * 384 + h * 32;
        float qk = 0.f;
        #pragma unroll
        for (int c = 0; c < 16; ++c) qk += qv[c] * kr[c];
        const float* kp = kvp + j * 432 + h * 36;
        float d2 = 0.f;
        #pragma unroll
        for (int e = 0; e < 12; ++e) { float df = qpv[e] - kp[e]; d2 += df * df; }
        row[j] = qk * SC_QK + arow[j] - sh_hw * d2 + (mi * mask[j] - 1.0f) * INFV;
    }
    __syncthreads();
    float v = fmaxf(row[t], row[t + 256]);
    for (int off = 32; off; off >>= 1) v = fmaxf(v, __shfl_xor(v, off));
    if ((t & 63) == 0) red[t >> 6] = v;
    __syncthreads();
    float mx = fmaxf(fmaxf(red[0], red[1]), fmaxf(red[2], red[3]));
    __syncthreads();
    float e0 = expf(row[t] - mx), e1 = expf(row[t + 256] - mx);
    float sv = e0 + e1;
    for (int off = 32; off; off >>= 1) sv += __shfl_xor(sv, off);
    if ((t & 63) == 0) red[t >> 6] = sv;
    __syncthreads();
    float inv = 1.0f / (red[0] + red[1] + red[2] + red[3]);
    arow[t] = e0 * inv;
    arow[t + 256] = e1 * inv;
}

// ---------------- O = A @ [v | vp] per head ----------------
__global__ void ov_kernel(const float* __restrict__ attn, const float* __restrict__ kv,
                          const float* __restrict__ kvp, float* __restrict__ cat,
                          float* __restrict__ opraw)
{
    __shared__ float As[32 * 65];
    __shared__ float Rs[64 * 41];
    const int t = threadIdx.x;
    const int i0 = blockIdx.x * 32, h = blockIdx.y;
    const int r = t >> 3, g = t & 7;
    float acc[5] = {0.f, 0.f, 0.f, 0.f, 0.f};
    for (int jt = 0; jt < 8; ++jt) {
        int j0 = jt * 64;
        for (int idx = t; idx < 2048; idx += 256) {
            int rr = idx >> 6, jj = idx & 63;
            As[rr * 65 + jj] = attn[((size_t)h * N + i0 + rr) * N + j0 + jj];
        }
        for (int idx = t; idx < 2560; idx += 256) {
            int jj = idx / 40, c = idx % 40;
            float vv;
            if (c < 16) vv = kv[(j0 + jj) * 384 + h * 32 + 16 + c];
            else        vv = kvp[(j0 + jj) * 432 + h * 36 + 12 + (c - 16)];
            Rs[jj * 41 + c] = vv;
        }
        __syncthreads();
        for (int jj = 0; jj < 64; ++jj) {
            float av = As[r * 65 + jj];
            #pragma unroll
            for (int c5 = 0; c5 < 5; ++c5) acc[c5] += av * Rs[jj * 41 + g * 5 + c5];
        }
        __syncthreads();
    }
    int i = i0 + r;
    #pragma unroll
    for (int c5 = 0; c5 < 5; ++c5) {
        int c = g * 5 + c5;
        if (c < 16) cat[(size_t)i * DCAT + h * 16 + c] = acc[c5];
        else        opraw[i * 288 + h * 24 + (c - 16)] = acc[c5];
    }
}

// ---------------- op finalize: R^T (op - t), norms ----------------
__global__ void opfin_kernel(const float* __restrict__ opraw, const float* __restrict__ rot,
                             const float* __restrict__ trans, float* __restrict__ cat)
{
    int gid = blockIdx.x * 256 + threadIdx.x;
    if (gid >= N * 96) return;
    int i = gid / 96, rem = gid % 96;
    int h = rem >> 3, pv = rem & 7;
    const float* o = opraw + i * 288 + h * 24 + pv * 3;
    const float* T = trans + i * 3;
    const float* R = rot + i * 9;
    float x = o[0] - T[0], y = o[1] - T[1], z = o[2] - T[2];
    float rx = R[0] * x + R[3] * y + R[6] * z;
    float ry = R[1] * x + R[4] * y + R[7] * z;
    float rz = R[2] * x + R[5] * y + R[8] * z;
    float nm = sqrtf(rx * rx + ry * ry + rz * rz + 1e-8f);
    float* cr = cat + (size_t)i * DCAT;
    cr[192 + h * 24 + pv * 3 + 0] = rx;
    cr[192 + h * 24 + pv * 3 + 1] = ry;
    cr[192 + h * 24 + pv * 3 + 2] = rz;
    cr[480 + h * 8 + pv] = nm;
}

// ---------------- o_pair[i,h,c] = sum_j a[h,i,j] p[i,j,c] ----------------
__global__ void opair_kernel(const float* __restrict__ attn, const float* __restrict__ p,
                             float* __restrict__ cat)
{
    __shared__ float Ps[4096];
    __shared__ float As[384];
    const int t = threadIdx.x, i = blockIdx.x;
    const int c = t & 127, g = t >> 7;
    float acc[6] = {0.f, 0.f, 0.f, 0.f, 0.f, 0.f};
    for (int jt = 0; jt < 16; ++jt) {
        int j0 = jt * 32;
        for (int idx = t; idx < 4096; idx += 256)
            Ps[idx] = p[((size_t)i * N + j0) * 128 + idx];
        for (int idx = t; idx < 384; idx += 256) {
            int h = idx >> 5, jj = idx & 31;
            As[idx] = attn[((size_t)h * N + i) * N + j0 + jj];
        }
        __syncthreads();
        for (int jj = 0; jj < 32; ++jj) {
            float pv = Ps[jj * 128 + c];
            #pragma unroll
            for (int hh = 0; hh < 6; ++hh)
                acc[hh] += As[(g * 6 + hh) * 32 + jj] * pv;
        }
        __syncthreads();
    }
    #pragma unroll
    for (int hh = 0; hh < 6; ++hh)
        cat[(size_t)i * DCAT + 576 + (g * 6 + hh) * 128 + c] = acc[hh];
}

// ---------------- layer norm (optional residual addend) ----------------
__global__ void ln_kernel(const float* __restrict__ x, const float* __restrict__ add,
                          const float* __restrict__ g, const float* __restrict__ b,
                          float* __restrict__ out)
{
    __shared__ float buf[384];
    __shared__ float red[2], red2[2];
    const int i = blockIdx.x, t = threadIdx.x;
    float s = 0.f, sq = 0.f;
    for (int k = t; k < 384; k += 128) {
        float v = x[(size_t)i * 384 + k];
        if (add) v += add[(size_t)i * 384 + k];
        buf[k] = v; s += v; sq += v * v;
    }
    for (int off = 32; off; off >>= 1) { s += __shfl_xor(s, off); sq += __shfl_xor(sq, off); }
    if ((t & 63) == 0) { red[t >> 6] = s; red2[t >> 6] = sq; }
    __syncthreads();
    float mean = (red[0] + red[1]) * (1.0f / 384.0f);
    float var = (red2[0] + red2[1]) * (1.0f / 384.0f) - mean * mean;
    float rstd = rsqrtf(var + 1e-5f);
    for (int k = t; k < 384; k += 128)
        out[(size_t)i * 384 + k] = (buf[k] - mean) * rstd * g[k] + b[k];
}

// ---------------- final: upd, quaternion, rot_new, trans_new ----------------
__global__ void final_kernel(const float* __restrict__ s2, const float* __restrict__ bb_w,
                             const float* __restrict__ bb_b, const float* __restrict__ rot,
                             const float* __restrict__ trans, float* __restrict__ out_rot,
                             float* __restrict__ out_trans)
{
    int i = blockIdx.x * 64 + threadIdx.x;
    if (i >= N) return;
    float u[6] = {0.f, 0.f, 0.f, 0.f, 0.f, 0.f};
    for (int k = 0; k < 384; ++k) {
        float sv = s2[(size_t)i * 384 + k];
        #pragma unroll
        for (int c = 0; c < 6; ++c) u[c] += sv * bb_w[k * 6 + c];
    }
    #pragma unroll
    for (int c = 0; c < 6; ++c) u[c] += bb_b[c];
    float inq = rsqrtf(1.0f + u[0] * u[0] + u[1] * u[1] + u[2] * u[2]);
    float w = inq, x = u[0] * inq, y = u[1] * inq, z = u[2] * inq;
    float Ru[9];
    Ru[0] = 1.f - 2.f * (y * y + z * z); Ru[1] = 2.f * (x * y - w * z); Ru[2] = 2.f * (x * z + w * y);
    Ru[3] = 2.f * (x * y + w * z); Ru[4] = 1.f - 2.f * (x * x + z * z); Ru[5] = 2.f * (y * z - w * x);
    Ru[6] = 2.f * (x * z - w * y); Ru[7] = 2.f * (y * z + w * x); Ru[8] = 1.f - 2.f * (x * x + y * y);
    const float* R = rot + i * 9;
    #pragma unroll
    for (int a = 0; a < 3; ++a) {
        #pragma unroll
        for (int cc = 0; cc < 3; ++cc)
            out_rot[i * 9 + a * 3 + cc] =
                R[a * 3 + 0] * Ru[0 + cc] + R[a * 3 + 1] * Ru[3 + cc] + R[a * 3 + 2] * Ru[6 + cc];
        out_trans[i * 3 + a] = R[a * 3 + 0] * u[3] + R[a * 3 + 1] * u[4] + R[a * 3 + 2] * u[5]
                               + trans[i * 3 + a];
    }
}

extern "C" void kernel_launch(void* const* d_in, const int* in_sizes, int n_in,
                              void* d_out, int out_size, void* d_ws, size_t ws_size,
                              hipStream_t stream)
{
    const float* s      = (const float*)d_in[0];
    const float* p      = (const float*)d_in[1];
    const float* rot    = (const float*)d_in[2];
    const float* trans  = (const float*)d_in[3];
    const float* mask   = (const float*)d_in[4];
    const float* w_q    = (const float*)d_in[5];
    const float* b_q    = (const float*)d_in[6];
    const float* w_kv   = (const float*)d_in[7];
    const float* b_kv   = (const float*)d_in[8];
    const float* w_qp   = (const float*)d_in[9];
    const float* b_qp   = (const float*)d_in[10];
    const float* w_kvp  = (const float*)d_in[11];
    const float* b_kvp  = (const float*)d_in[12];
    const float* w_b    = (const float*)d_in[13];
    const float* b_b    = (const float*)d_in[14];
    const float* head_w = (const float*)d_in[15];
    const float* w_o    = (const float*)d_in[16];
    const float* b_o    = (const float*)d_in[17];
    const float* ln1_g  = (const float*)d_in[18];
    const float* ln1_b  = (const float*)d_in[19];
    const float* tw1    = (const float*)d_in[20];
    const float* tb1    = (const float*)d_in[21];
    const float* tw2    = (const float*)d_in[22];
    const float* tb2    = (const float*)d_in[23];
    const float* tw3    = (const float*)d_in[24];
    const float* tb3    = (const float*)d_in[25];
    const float* ln2_g  = (const float*)d_in[26];
    const float* ln2_b  = (const float*)d_in[27];
    const float* bb_w   = (const float*)d_in[28];
    const float* bb_b   = (const float*)d_in[29];

    float* ws   = (float*)d_ws;
    float* wq   = ws;               // 512*192   = 98304
    float* wkv  = wq + 98304;       // 512*384   = 196608
    float* wqp  = wkv + 196608;     // 512*144   = 73728
    float* wkvp = wqp + 73728;      // 512*432   = 221184
    float* attn = wkvp + 221184;    // 12*512*512= 3145728
    float* cat  = attn + 3145728;   // 512*2112  = 1081344
    float* opr  = cat + 1081344;    // 512*288   = 147456
    float* s1p  = opr + 147456;     // 196608
    float* s1   = s1p + 196608;     // 196608
    float* h1   = s1 + 196608;      // 196608
    float* h2   = h1 + 196608;      // 196608

    float* out_s     = (float*)d_out;
    float* out_rot   = out_s + 196608;
    float* out_trans = out_rot + 4608;

    // projections
    gemm_rows<<<dim3(128, 1), 192, 4 * 384 * 4, stream>>>(s, w_q, b_q, nullptr, wq, 384, 192, 0);
    gemm_rows<<<dim3(128, 2), 192, 4 * 384 * 4, stream>>>(s, w_kv, b_kv, nullptr, wkv, 384, 384, 0);
    gemm_rows<<<dim3(128, 1), 192, 4 * 384 * 4, stream>>>(s, w_qp, b_qp, nullptr, wqp, 384, 144, 0);
    gemm_rows<<<dim3(128, 3), 192, 4 * 384 * 4, stream>>>(s, w_kvp, b_kvp, nullptr, wkvp, 384, 432, 0);
    rotate_pts<<<(512 * 48 + 255) / 256, 256, 0, stream>>>(wqp, rot, trans, 48);
    rotate_pts<<<(512 * 144 + 255) / 256, 256, 0, stream>>>(wkvp, rot, trans, 144);
    // bias (writes attn buffer, transposed)
    bias_kernel<<<NN / 32, 256, 0, stream>>>(p, w_b, b_b, attn);
    // logits + softmax in place
    attn_kernel<<<dim3(512, 12), 256, 0, stream>>>(wq, wkv, wqp, wkvp, head_w, mask, attn);
    // A @ [v|vp]
    ov_kernel<<<dim3(16, 12), 256, 0, stream>>>(attn, wkv, wkvp, cat, opr);
    opfin_kernel<<<192, 256, 0, stream>>>(opr, rot, trans, cat);
    // o_pair
    opair_kernel<<<512, 256, 0, stream>>>(attn, p, cat);
    // output projection + residual
    gemm_rows<<<dim3(128, 2), 192, 4 * 2112 * 4, stream>>>(cat, w_o, b_o, s, s1p, 2112, 384, 0);
    ln_kernel<<<512, 128, 0, stream>>>(s1p, nullptr, ln1_g, ln1_b, s1);
    // transition
    gemm_rows<<<dim3(128, 2), 192, 4 * 384 * 4, stream>>>(s1, tw1, tb1, nullptr, h1, 384, 384, 1);
    gemm_rows<<<dim3(128, 2), 192, 4 * 384 * 4, stream>>>(h1, tw2, tb2, nullptr, h2, 384, 384, 1);
    gemm_rows<<<dim3(128, 2), 192, 4 * 384 * 4, stream>>>(h2, tw3, tb3, nullptr, s1p, 384, 384, 0);
    ln_kernel<<<512, 128, 0, stream>>>(s1p, s1, ln2_g, ln2_b, out_s);
    // rigid update
    final_kernel<<<8, 64, 0, stream>>>(out_s, bb_w, bb_b, rot, trans, out_rot, out_trans);
}

// Round 2
// 592.819 us; speedup vs baseline: 1.1840x; 1.1840x over previous
//
#include <hip/hip_runtime.h>
#include <math.h>

#define N 512
#define CS 384
#define CP 128
#define CH 16
#define NH 12
#define NN (N*N)
#define DCAT 2112
#define INFV 100000.0f

__device__ __constant__ float SC_QK = 0.14433756729740643f; // sqrt(1/48)
#define SC_B  0.57735026918962576f  // sqrt(1/3)
#define HW_SC 0.13608276348795434f  // sqrt(1/54)

typedef __attribute__((ext_vector_type(8))) short bf16x8;
typedef __attribute__((ext_vector_type(4))) float f32x4;

__device__ inline short f2bf(float v) {
    unsigned u = __builtin_bit_cast(unsigned, v);
    u += 0x7FFF + ((u >> 16) & 1);   // round-to-nearest-even
    return (short)(u >> 16);
}

#define BKP 40  // padded LDS k-stride (32 + 8), keeps 16B alignment, spreads banks

// ---------------- bf16 MFMA GEMM: Y[512 x KOUT] = X[512 x KIN] @ W (+bias)(+resid)(relu) ----
// 64x64 tile per block, BK=32, 256 threads = 4 waves, each wave a 32x32 quadrant
// (2x2 fragments of mfma_f32_16x16x32_bf16). f32 accumulate, f32 I/O.
__global__ __launch_bounds__(256) void gemm_mfma(
    const float* __restrict__ X, const float* __restrict__ W,
    const float* __restrict__ bias, const float* __restrict__ resid,
    float* __restrict__ Y, int KIN, int KOUT, int relu)
{
    __shared__ short As[64 * BKP];
    __shared__ short Bs[64 * BKP];
    const int t = threadIdx.x;
    const int i0 = blockIdx.x * 64, n0 = blockIdx.y * 64;
    const int w = t >> 6, l = t & 63;
    const int r0 = (w >> 1) * 32, c0 = (w & 1) * 32;
    const int lr = l & 15, lk = (l >> 4) * 8;

    f32x4 acc[2][2];
    #pragma unroll
    for (int m = 0; m < 2; ++m)
        #pragma unroll
        for (int n = 0; n < 2; ++n) acc[m][n] = (f32x4){0.f, 0.f, 0.f, 0.f};

    // staging indices: A: thread covers (row, 8 k); B: (k, 8 n) then transpose-write
    const int ar = t >> 2, ak = (t & 3) * 8;
    const int bk = t >> 3, bn = (t & 7) * 8;

    for (int k0 = 0; k0 < KIN; k0 += 32) {
        // stage A tile (64 rows x 32 k), f32 -> bf16, contiguous 16B LDS writes
        {
            const float* xa = X + (size_t)(i0 + ar) * KIN + k0 + ak;
            f32x4 v0 = *(const f32x4*)(xa);
            f32x4 v1 = *(const f32x4*)(xa + 4);
            bf16x8 pk;
            pk[0] = f2bf(v0[0]); pk[1] = f2bf(v0[1]); pk[2] = f2bf(v0[2]); pk[3] = f2bf(v0[3]);
            pk[4] = f2bf(v1[0]); pk[5] = f2bf(v1[1]); pk[6] = f2bf(v1[2]); pk[7] = f2bf(v1[3]);
            *(bf16x8*)(As + ar * BKP + ak) = pk;
        }
        // stage B tile (32 k x 64 n) transposed into Bs[n][k]
        {
            const float* wb = W + (size_t)(k0 + bk) * KOUT + n0 + bn;
            #pragma unroll
            for (int j = 0; j < 8; ++j) {
                float v = (n0 + bn + j < KOUT) ? wb[j] : 0.f;
                Bs[(bn + j) * BKP + bk] = f2bf(v);
            }
        }
        __syncthreads();
        bf16x8 a[2], b[2];
        #pragma unroll
        for (int m = 0; m < 2; ++m)
            a[m] = *(const bf16x8*)(As + (r0 + m * 16 + lr) * BKP + lk);
        #pragma unroll
        for (int n = 0; n < 2; ++n)
            b[n] = *(const bf16x8*)(Bs + (c0 + n * 16 + lr) * BKP + lk);
        #pragma unroll
        for (int m = 0; m < 2; ++m)
            #pragma unroll
            for (int n = 0; n < 2; ++n)
                acc[m][n] = __builtin_amdgcn_mfma_f32_16x16x32_bf16(a[m], b[n], acc[m][n], 0, 0, 0);
        __syncthreads();
    }
    // epilogue: C/D layout col = lane&15, row = (lane>>4)*4 + j
    #pragma unroll
    for (int m = 0; m < 2; ++m)
        #pragma unroll
        for (int n = 0; n < 2; ++n) {
            int col = n0 + c0 + n * 16 + lr;
            if (col >= KOUT) continue;
            float bv = bias[col];
            #pragma unroll
            for (int j = 0; j < 4; ++j) {
                int row = i0 + r0 + m * 16 + (l >> 4) * 4 + j;
                float o = acc[m][n][j] + bv;
                if (resid) o += resid[(size_t)row * KOUT + col];
                if (relu) o = fmaxf(o, 0.f);
                Y[(size_t)row * KOUT + col] = o;
            }
        }
}

// ---------------- rotate points in place: v <- R v + t ----------------
__global__ void rotate_pts(float* __restrict__ pts, const float* __restrict__ rot,
                           const float* __restrict__ trans, int P)
{
    int gid = blockIdx.x * 256 + threadIdx.x;
    if (gid >= N * P) return;
    int n = gid / P;
    float* v = pts + (size_t)gid * 3;
    float x = v[0], y = v[1], z = v[2];
    const float* R = rot + n * 9;
    const float* T = trans + n * 3;
    v[0] = R[0] * x + R[1] * y + R[2] * z + T[0];
    v[1] = R[3] * x + R[4] * y + R[5] * z + T[1];
    v[2] = R[6] * x + R[7] * y + R[8] * z + T[2];
}

// ---------------- bias = sqrt(1/3) * (p @ w_b + b_b), stored transposed (h, i*N+j) ----------------
__global__ void bias_kernel(const float* __restrict__ p, const float* __restrict__ w_b,
                            const float* __restrict__ b_b, float* __restrict__ attn)
{
    __shared__ float Ps[32 * 130];
    __shared__ float Wb[CP * NH];
    const int t = threadIdx.x;
    const int m0 = blockIdx.x * 32;
    for (int idx = t; idx < 4096; idx += 256) {
        int jj = idx >> 7, c = idx & 127;
        Ps[jj * 130 + c] = p[(size_t)m0 * 128 + idx];
    }
    for (int idx = t; idx < CP * NH; idx += 256) Wb[idx] = w_b[idx];
    __syncthreads();
    for (int o = t; o < 384; o += 256) {
        int r = o & 31, h = o >> 5;
        float acc = 0.f;
        for (int c = 0; c < 128; ++c) acc += Ps[r * 130 + c] * Wb[c * 12 + h];
        attn[(size_t)h * NN + m0 + r] = SC_B * (acc + b_b[h]);
    }
}

// ---------------- logits (qk + bias + point term + mask) + softmax, in place ----------------
__global__ void attn_kernel(const float* __restrict__ q, const float* __restrict__ kv,
                            const float* __restrict__ qp, const float* __restrict__ kvp,
                            const float* __restrict__ head_w, const float* __restrict__ mask,
                            float* __restrict__ attn)
{
    __shared__ float qv[16], qpv[12], row[512], red[4];
    __shared__ float sh_hw;
    const int i = blockIdx.x, h = blockIdx.y, t = threadIdx.x;
    if (t < 16) qv[t] = q[i * 192 + h * 16 + t];
    if (t < 12) qpv[t] = qp[i * 144 + h * 12 + t];
    if (t == 0) sh_hw = 0.5f * HW_SC * log1pf(expf(head_w[h]));
    __syncthreads();
    float mi = mask[i];
    float* arow = attn + ((size_t)h * N + i) * N;
    for (int j = t; j < N; j += 256) {
        const float* kr = kv + j * 384 + h * 32;
        float qk = 0.f;
        #pragma unroll
        for (int c = 0; c < 16; ++c) qk += qv[c] * kr[c];
        const float* kp = kvp + j * 432 + h * 36;
        float d2 = 0.f;
        #pragma unroll
        for (int e = 0; e < 12; ++e) { float df = qpv[e] - kp[e]; d2 += df * df; }
        row[j] = qk * SC_QK + arow[j] - sh_hw * d2 + (mi * mask[j] - 1.0f) * INFV;
    }
    __syncthreads();
    float v = fmaxf(row[t], row[t + 256]);
    for (int off = 32; off; off >>= 1) v = fmaxf(v, __shfl_xor(v, off));
    if ((t & 63) == 0) red[t >> 6] = v;
    __syncthreads();
    float mx = fmaxf(fmaxf(red[0], red[1]), fmaxf(red[2], red[3]));
    __syncthreads();
    float e0 = expf(row[t] - mx), e1 = expf(row[t + 256] - mx);
    float sv = e0 + e1;
    for (int off = 32; off; off >>= 1) sv += __shfl_xor(sv, off);
    if ((t & 63) == 0) red[t >> 6] = sv;
    __syncthreads();
    float inv = 1.0f / (red[0] + red[1] + red[2] + red[3]);
    arow[t] = e0 * inv;
    arow[t + 256] = e1 * inv;
}

// ---------------- O = A @ [v | vp] per head ----------------
__global__ void ov_kernel(const float* __restrict__ attn, const float* __restrict__ kv,
                          const float* __restrict__ kvp, float* __restrict__ cat,
                          float* __restrict__ opraw)
{
    __shared__ float As[32 * 65];
    __shared__ float Rs[64 * 41];
    const int t = threadIdx.x;
    const int i0 = blockIdx.x * 32, h = blockIdx.y;
    const int r = t >> 3, g = t & 7;
    float acc[5] = {0.f, 0.f, 0.f, 0.f, 0.f};
    for (int jt = 0; jt < 8; ++jt) {
        int j0 = jt * 64;
        for (int idx = t; idx < 2048; idx += 256) {
            int rr = idx >> 6, jj = idx & 63;
            As[rr * 65 + jj] = attn[((size_t)h * N + i0 + rr) * N + j0 + jj];
        }
        for (int idx = t; idx < 2560; idx += 256) {
            int jj = idx / 40, c = idx % 40;
            float vv;
            if (c < 16) vv = kv[(j0 + jj) * 384 + h * 32 + 16 + c];
            else        vv = kvp[(j0 + jj) * 432 + h * 36 + 12 + (c - 16)];
            Rs[jj * 41 + c] = vv;
        }
        __syncthreads();
        for (int jj = 0; jj < 64; ++jj) {
            float av = As[r * 65 + jj];
            #pragma unroll
            for (int c5 = 0; c5 < 5; ++c5) acc[c5] += av * Rs[jj * 41 + g * 5 + c5];
        }
        __syncthreads();
    }
    int i = i0 + r;
    #pragma unroll
    for (int c5 = 0; c5 < 5; ++c5) {
        int c = g * 5 + c5;
        if (c < 16) cat[(size_t)i * DCAT + h * 16 + c] = acc[c5];
        else        opraw[i * 288 + h * 24 + (c - 16)] = acc[c5];
    }
}

// ---------------- op finalize: R^T (op - t), norms ----------------
__global__ void opfin_kernel(const float* __restrict__ opraw, const float* __restrict__ rot,
                             const float* __restrict__ trans, float* __restrict__ cat)
{
    int gid = blockIdx.x * 256 + threadIdx.x;
    if (gid >= N * 96) return;
    int i = gid / 96, rem = gid % 96;
    int h = rem >> 3, pv = rem & 7;
    const float* o = opraw + i * 288 + h * 24 + pv * 3;
    const float* T = trans + i * 3;
    const float* R = rot + i * 9;
    float x = o[0] - T[0], y = o[1] - T[1], z = o[2] - T[2];
    float rx = R[0] * x + R[3] * y + R[6] * z;
    float ry = R[1] * x + R[4] * y + R[7] * z;
    float rz = R[2] * x + R[5] * y + R[8] * z;
    float nm = sqrtf(rx * rx + ry * ry + rz * rz + 1e-8f);
    float* cr = cat + (size_t)i * DCAT;
    cr[192 + h * 24 + pv * 3 + 0] = rx;
    cr[192 + h * 24 + pv * 3 + 1] = ry;
    cr[192 + h * 24 + pv * 3 + 2] = rz;
    cr[480 + h * 8 + pv] = nm;
}

// ---------------- o_pair[i,h,c] = sum_j a[h,i,j] p[i,j,c] ----------------
__global__ void opair_kernel(const float* __restrict__ attn, const float* __restrict__ p,
                             float* __restrict__ cat)
{
    __shared__ float Ps[4096];
    __shared__ float As[384];
    const int t = threadIdx.x, i = blockIdx.x;
    const int c = t & 127, g = t >> 7;
    float acc[6] = {0.f, 0.f, 0.f, 0.f, 0.f, 0.f};
    for (int jt = 0; jt < 16; ++jt) {
        int j0 = jt * 32;
        for (int idx = t; idx < 4096; idx += 256)
            Ps[idx] = p[((size_t)i * N + j0) * 128 + idx];
        for (int idx = t; idx < 384; idx += 256) {
            int h = idx >> 5, jj = idx & 31;
            As[idx] = attn[((size_t)h * N + i) * N + j0 + jj];
        }
        __syncthreads();
        for (int jj = 0; jj < 32; ++jj) {
            float pv = Ps[jj * 128 + c];
            #pragma unroll
            for (int hh = 0; hh < 6; ++hh)
                acc[hh] += As[(g * 6 + hh) * 32 + jj] * pv;
        }
        __syncthreads();
    }
    #pragma unroll
    for (int hh = 0; hh < 6; ++hh)
        cat[(size_t)i * DCAT + 576 + (g * 6 + hh) * 128 + c] = acc[hh];
}

// ---------------- layer norm (optional residual addend) ----------------
__global__ void ln_kernel(const float* __restrict__ x, const float* __restrict__ add,
                          const float* __restrict__ g, const float* __restrict__ b,
                          float* __restrict__ out)
{
    __shared__ float buf[384];
    __shared__ float red[2], red2[2];
    const int i = blockIdx.x, t = threadIdx.x;
    float s = 0.f, sq = 0.f;
    for (int k = t; k < 384; k += 128) {
        float v = x[(size_t)i * 384 + k];
        if (add) v += add[(size_t)i * 384 + k];
        buf[k] = v; s += v; sq += v * v;
    }
    for (int off = 32; off; off >>= 1) { s += __shfl_xor(s, off); sq += __shfl_xor(sq, off); }
    if ((t & 63) == 0) { red[t >> 6] = s; red2[t >> 6] = sq; }
    __syncthreads();
    float mean = (red[0] + red[1]) * (1.0f / 384.0f);
    float var = (red2[0] + red2[1]) * (1.0f / 384.0f) - mean * mean;
    float rstd = rsqrtf(var + 1e-5f);
    for (int k = t; k < 384; k += 128)
        out[(size_t)i * 384 + k] = (buf[k] - mean) * rstd * g[k] + b[k];
}

// ---------------- final: upd, quaternion, rot_new, trans_new ----------------
__global__ void final_kernel(const float* __restrict__ s2, const float* __restrict__ bb_w,
                             const float* __restrict__ bb_b, const float* __restrict__ rot,
                             const float* __restrict__ trans, float* __restrict__ out_rot,
                             float* __restrict__ out_trans)
{
    int i = blockIdx.x * 64 + threadIdx.x;
    if (i >= N) return;
    float u[6] = {0.f, 0.f, 0.f, 0.f, 0.f, 0.f};
    for (int k = 0; k < 384; ++k) {
        float sv = s2[(size_t)i * 384 + k];
        #pragma unroll
        for (int c = 0; c < 6; ++c) u[c] += sv * bb_w[k * 6 + c];
    }
    #pragma unroll
    for (int c = 0; c < 6; ++c) u[c] += bb_b[c];
    float inq = rsqrtf(1.0f + u[0] * u[0] + u[1] * u[1] + u[2] * u[2]);
    float w = inq, x = u[0] * inq, y = u[1] * inq, z = u[2] * inq;
    float Ru[9];
    Ru[0] = 1.f - 2.f * (y * y + z * z); Ru[1] = 2.f * (x * y - w * z); Ru[2] = 2.f * (x * z + w * y);
    Ru[3] = 2.f * (x * y + w * z); Ru[4] = 1.f - 2.f * (x * x + z * z); Ru[5] = 2.f * (y * z - w * x);
    Ru[6] = 2.f * (x * z - w * y); Ru[7] = 2.f * (y * z + w * x); Ru[8] = 1.f - 2.f * (x * x + y * y);
    const float* R = rot + i * 9;
    #pragma unroll
    for (int a = 0; a < 3; ++a) {
        #pragma unroll
        for (int cc = 0; cc < 3; ++cc)
            out_rot[i * 9 + a * 3 + cc] =
                R[a * 3 + 0] * Ru[0 + cc] + R[a * 3 + 1] * Ru[3 + cc] + R[a * 3 + 2] * Ru[6 + cc];
        out_trans[i * 3 + a] = R[a * 3 + 0] * u[3] + R[a * 3 + 1] * u[4] + R[a * 3 + 2] * u[5]
                               + trans[i * 3 + a];
    }
}

extern "C" void kernel_launch(void* const* d_in, const int* in_sizes, int n_in,
                              void* d_out, int out_size, void* d_ws, size_t ws_size,
                              hipStream_t stream)
{
    const float* s      = (const float*)d_in[0];
    const float* p      = (const float*)d_in[1];
    const float* rot    = (const float*)d_in[2];
    const float* trans  = (const float*)d_in[3];
    const float* mask   = (const float*)d_in[4];
    const float* w_q    = (const float*)d_in[5];
    const float* b_q    = (const float*)d_in[6];
    const float* w_kv   = (const float*)d_in[7];
    const float* b_kv   = (const float*)d_in[8];
    const float* w_qp   = (const float*)d_in[9];
    const float* b_qp   = (const float*)d_in[10];
    const float* w_kvp  = (const float*)d_in[11];
    const float* b_kvp  = (const float*)d_in[12];
    const float* w_b    = (const float*)d_in[13];
    const float* b_b    = (const float*)d_in[14];
    const float* head_w = (const float*)d_in[15];
    const float* w_o    = (const float*)d_in[16];
    const float* b_o    = (const float*)d_in[17];
    const float* ln1_g  = (const float*)d_in[18];
    const float* ln1_b  = (const float*)d_in[19];
    const float* tw1    = (const float*)d_in[20];
    const float* tb1    = (const float*)d_in[21];
    const float* tw2    = (const float*)d_in[22];
    const float* tb2    = (const float*)d_in[23];
    const float* tw3    = (const float*)d_in[24];
    const float* tb3    = (const float*)d_in[25];
    const float* ln2_g  = (const float*)d_in[26];
    const float* ln2_b  = (const float*)d_in[27];
    const float* bb_w   = (const float*)d_in[28];
    const float* bb_b   = (const float*)d_in[29];

    float* ws   = (float*)d_ws;
    float* wq   = ws;               // 512*192   = 98304
    float* wkv  = wq + 98304;       // 512*384   = 196608
    float* wqp  = wkv + 196608;     // 512*144   = 73728
    float* wkvp = wqp + 73728;      // 512*432   = 221184
    float* attn = wkvp + 221184;    // 12*512*512= 3145728
    float* cat  = attn + 3145728;   // 512*2112  = 1081344
    float* opr  = cat + 1081344;    // 512*288   = 147456
    float* s1p  = opr + 147456;     // 196608
    float* s1   = s1p + 196608;     // 196608
    float* h1   = s1 + 196608;      // 196608
    float* h2   = h1 + 196608;      // 196608

    float* out_s     = (float*)d_out;
    float* out_rot   = out_s + 196608;
    float* out_trans = out_rot + 4608;

    // projections (bf16 MFMA)
    gemm_mfma<<<dim3(8, 3), 256, 0, stream>>>(s, w_q, b_q, nullptr, wq, 384, 192, 0);
    gemm_mfma<<<dim3(8, 6), 256, 0, stream>>>(s, w_kv, b_kv, nullptr, wkv, 384, 384, 0);
    gemm_mfma<<<dim3(8, 3), 256, 0, stream>>>(s, w_qp, b_qp, nullptr, wqp, 384, 144, 0);
    gemm_mfma<<<dim3(8, 7), 256, 0, stream>>>(s, w_kvp, b_kvp, nullptr, wkvp, 384, 432, 0);
    rotate_pts<<<(512 * 48 + 255) / 256, 256, 0, stream>>>(wqp, rot, trans, 48);
    rotate_pts<<<(512 * 144 + 255) / 256, 256, 0, stream>>>(wkvp, rot, trans, 144);
    // bias (writes attn buffer, transposed)
    bias_kernel<<<NN / 32, 256, 0, stream>>>(p, w_b, b_b, attn);
    // logits + softmax in place
    attn_kernel<<<dim3(512, 12), 256, 0, stream>>>(wq, wkv, wqp, wkvp, head_w, mask, attn);
    // A @ [v|vp]
    ov_kernel<<<dim3(16, 12), 256, 0, stream>>>(attn, wkv, wkvp, cat, opr);
    opfin_kernel<<<192, 256, 0, stream>>>(opr, rot, trans, cat);
    // o_pair
    opair_kernel<<<512, 256, 0, stream>>>(attn, p, cat);
    // output projection + residual
    gemm_mfma<<<dim3(8, 6), 256, 0, stream>>>(cat, w_o, b_o, s, s1p, 2112, 384, 0);
    ln_kernel<<<512, 128, 0, stream>>>(s1p, nullptr, ln1_g, ln1_b, s1);
    // transition
    gemm_mfma<<<dim3(8, 6), 256, 0, stream>>>(s1, tw1, tb1, nullptr, h1, 384, 384, 1);
    gemm_mfma<<<dim3(8, 6), 256, 0, stream>>>(h1, tw2, tb2, nullptr, h2, 384, 384, 1);
    gemm_mfma<<<dim3(8, 6), 256, 0, stream>>>(h2, tw3, tb3, nullptr, s1p, 384, 384, 0);
    ln_kernel<<<512, 128, 0, stream>>>(s1p, s1, ln2_g, ln2_b, out_s);
    // rigid update
    final_kernel<<<8, 64, 0, stream>>>(out_s, bb_w, bb_b, rot, trans, out_rot, out_trans);
}

// Round 3
// 385.205 us; speedup vs baseline: 1.8222x; 1.5390x over previous
//
#include <hip/hip_runtime.h>
#include <math.h>

#define N 512
#define CS 384
#define CP 128
#define CH 16
#define NH 12
#define NN (N*N)
#define DCAT 2112
#define DQKV 1152
#define INFV 100000.0f

__device__ __constant__ float SC_QK = 0.14433756729740643f; // sqrt(1/48)
#define SC_B  0.57735026918962576f  // sqrt(1/3)
#define HW_SC 0.13608276348795434f  // sqrt(1/54)

typedef __attribute__((ext_vector_type(8))) short bf16x8;
typedef __attribute__((ext_vector_type(4))) float f32x4;
typedef __attribute__((ext_vector_type(4))) short sh4;
typedef unsigned short ushort_t;

__device__ inline short f2bf(float v) {
    unsigned u = __builtin_bit_cast(unsigned, v);
    u += 0x7FFF + ((u >> 16) & 1);   // round-to-nearest-even
    return (short)(u >> 16);
}

__device__ __forceinline__ void gload16(const void* g, void* l) {
    __builtin_amdgcn_global_load_lds(
        (const __attribute__((address_space(1))) unsigned int*)g,
        (__attribute__((address_space(3))) unsigned int*)l,
        16, 0, 0);
}

// ============ transpose-convert: src f32 [K][Nc] -> dst bf16 [Nc][K] (dst row stride K) ======
__global__ void tc_kernel(const float* __restrict__ src, int Nc, int K,
                          ushort_t* __restrict__ dst)
{
    __shared__ float tile[32][33];
    const int cx = blockIdx.x * 32, ky = blockIdx.y * 32;
    const int tx = threadIdx.x & 31, ty = threadIdx.x >> 5;
    for (int r = ty; r < 32; r += 8) {
        int c = cx + tx;
        tile[r][tx] = (c < Nc) ? src[(size_t)(ky + r) * Nc + c] : 0.f;
    }
    __syncthreads();
    for (int r = ty; r < 32; r += 8) {
        int outRow = cx + r;
        if (outRow < Nc)
            dst[(size_t)outRow * K + ky + tx] = (ushort_t)f2bf(tile[tx][r]);
    }
}

// ============ f32 -> bf16 convert (count multiple of 1024) ============
__global__ void conv_kernel(const float* __restrict__ src, ushort_t* __restrict__ dst, int n4)
{
    int i4 = blockIdx.x * 256 + threadIdx.x;
    if (i4 >= n4) return;
    f32x4 v = *(const f32x4*)(src + i4 * 4);
    sh4 o;
    o[0] = f2bf(v[0]); o[1] = f2bf(v[1]); o[2] = f2bf(v[2]); o[3] = f2bf(v[3]);
    *(sh4*)(dst + i4 * 4) = o;
}

// ============ bf16 MFMA GEMM, 64x64 tile, BK=32, 2-phase pipelined, split-K ============
// A bf16 [512][K], Bt bf16 [KOUT][K]; writes f32 partial [sp][512][KOUT]
__global__ __launch_bounds__(256) void gemm_bf16(
    const ushort_t* __restrict__ A, const ushort_t* __restrict__ Bt,
    float* __restrict__ part, int K, int KOUT, int nk)
{
    __shared__ __align__(16) ushort_t As[2][2048]; // 2 x 64rows x 32k
    __shared__ __align__(16) ushort_t Bs[2][2048];
    const int t = threadIdx.x, w = t >> 6, l = t & 63;
    const int i0 = blockIdx.x * 64, n0 = blockIdx.y * 64, sp = blockIdx.z;
    const int kbase = sp * nk * 32;

    // staging: wave w stages tile rows w*16..w*16+15; lane l -> (row, phys slot)
    const int srow = w * 16 + (l >> 2);
    const int skb = (l & 3) ^ ((srow >> 1) & 3);      // logical k-block at this phys slot
    const ushort_t* aSrc = A + (size_t)(i0 + srow) * K + kbase + skb * 8;
    const ushort_t* bSrc = Bt + (size_t)(n0 + srow) * K + kbase + skb * 8;
    ushort_t* aDst = &As[0][0] + w * 512;   // wave-uniform base (1KB per wave)
    ushort_t* bDst = &Bs[0][0] + w * 512;

    // fragment read byte-offsets (within a 4KB buffer), swizzled
    const int r0 = (w >> 1) * 32, c0 = (w & 1) * 32, lr = l & 15, hk = l >> 4;
    int aOff[2], bOff[2];
    #pragma unroll
    for (int m = 0; m < 2; ++m) {
        int row = r0 + m * 16 + lr;
        aOff[m] = row * 64 + ((hk ^ ((row >> 1) & 3)) << 4);
    }
    #pragma unroll
    for (int n = 0; n < 2; ++n) {
        int row = c0 + n * 16 + lr;
        bOff[n] = row * 64 + ((hk ^ ((row >> 1) & 3)) << 4);
    }

    f32x4 acc[2][2];
    #pragma unroll
    for (int m = 0; m < 2; ++m)
        #pragma unroll
        for (int n = 0; n < 2; ++n) acc[m][n] = (f32x4){0.f, 0.f, 0.f, 0.f};

    // prologue: stage k-step 0 into buf 0
    gload16(aSrc, aDst);
    gload16(bSrc, bDst);
    __syncthreads();

    int cur = 0;
    for (int it = 0; it < nk; ++it) {
        if (it + 1 < nk) {   // issue next-tile loads first (overlap with compute)
            gload16(aSrc + (it + 1) * 32, aDst + (cur ^ 1) * 2048);
            gload16(bSrc + (it + 1) * 32, bDst + (cur ^ 1) * 2048);
        }
        const char* ab = (const char*)&As[cur][0];
        const char* bb = (const char*)&Bs[cur][0];
        bf16x8 a0 = *(const bf16x8*)(ab + aOff[0]);
        bf16x8 a1 = *(const bf16x8*)(ab + aOff[1]);
        bf16x8 b0 = *(const bf16x8*)(bb + bOff[0]);
        bf16x8 b1 = *(const bf16x8*)(bb + bOff[1]);
        acc[0][0] = __builtin_amdgcn_mfma_f32_16x16x32_bf16(a0, b0, acc[0][0], 0, 0, 0);
        acc[0][1] = __builtin_amdgcn_mfma_f32_16x16x32_bf16(a0, b1, acc[0][1], 0, 0, 0);
        acc[1][0] = __builtin_amdgcn_mfma_f32_16x16x32_bf16(a1, b0, acc[1][0], 0, 0, 0);
        acc[1][1] = __builtin_amdgcn_mfma_f32_16x16x32_bf16(a1, b1, acc[1][1], 0, 0, 0);
        __syncthreads();   // drains vmcnt(0)+lgkmcnt(0): next buf staged, this buf free
        cur ^= 1;
    }

    // epilogue: partial write. C/D: col = lane&15, row = (lane>>4)*4 + j
    #pragma unroll
    for (int m = 0; m < 2; ++m)
        #pragma unroll
        for (int n = 0; n < 2; ++n) {
            int col = n0 + c0 + n * 16 + lr;
            int rowb = i0 + r0 + m * 16 + (l >> 4) * 4;
            float* pr = part + ((size_t)sp * 512 + rowb) * KOUT + col;
            #pragma unroll
            for (int j = 0; j < 4; ++j)
                pr[(size_t)j * KOUT] = acc[m][n][j];
        }
}

// ============ reduce split-K partials + bias (+resid)(+relu) -> f32 and/or bf16 ============
__global__ void reduce_k(const float* __restrict__ parts, int S, int KOUT,
                         const float* __restrict__ bias, const float* __restrict__ resid,
                         int relu, float* __restrict__ outf, ushort_t* __restrict__ outbf)
{
    int i4 = blockIdx.x * 256 + threadIdx.x;
    int tot = 512 * KOUT / 4;
    if (i4 >= tot) return;
    int idx = i4 * 4, c = idx % KOUT;
    f32x4 v = *(const f32x4*)(bias + c);
    for (int s2 = 0; s2 < S; ++s2)
        v += *(const f32x4*)(parts + (size_t)s2 * 512 * KOUT + idx);
    if (resid) v += *(const f32x4*)(resid + idx);
    if (relu) {
        v[0] = fmaxf(v[0], 0.f); v[1] = fmaxf(v[1], 0.f);
        v[2] = fmaxf(v[2], 0.f); v[3] = fmaxf(v[3], 0.f);
    }
    if (outf) *(f32x4*)(outf + idx) = v;
    if (outbf) {
        sh4 o;
        o[0] = f2bf(v[0]); o[1] = f2bf(v[1]); o[2] = f2bf(v[2]); o[3] = f2bf(v[3]);
        *(sh4*)(outbf + idx) = o;
    }
}

// ============ rotate points in fused qkv buffer: v <- R v + t ============
__global__ void rotate_pts(float* __restrict__ base, const float* __restrict__ rot,
                           const float* __restrict__ trans, int coloff, int P)
{
    int gid = blockIdx.x * 256 + threadIdx.x;
    if (gid >= N * P) return;
    int n = gid / P, pp = gid % P;
    float* v = base + (size_t)n * DQKV + coloff + pp * 3;
    float x = v[0], y = v[1], z = v[2];
    const float* R = rot + n * 9;
    const float* T = trans + n * 3;
    v[0] = R[0] * x + R[1] * y + R[2] * z + T[0];
    v[1] = R[3] * x + R[4] * y + R[5] * z + T[1];
    v[2] = R[6] * x + R[7] * y + R[8] * z + T[2];
}

// ============ bias = sqrt(1/3)*(p @ w_b + b_b), stored transposed (h, i*N+j) ============
__global__ void bias_kernel(const float* __restrict__ p, const float* __restrict__ w_b,
                            const float* __restrict__ b_b, float* __restrict__ attn)
{
    __shared__ float Ps[32 * 130];
    __shared__ float Wb[CP * NH];
    const int t = threadIdx.x;
    const int m0 = blockIdx.x * 32;
    for (int idx = t; idx < 4096; idx += 256) {
        int jj = idx >> 7, c = idx & 127;
        Ps[jj * 130 + c] = p[(size_t)m0 * 128 + idx];
    }
    for (int idx = t; idx < CP * NH; idx += 256) Wb[idx] = w_b[idx];
    __syncthreads();
    for (int o = t; o < 384; o += 256) {
        int r = o & 31, h = o >> 5;
        float acc = 0.f;
        for (int c = 0; c < 128; ++c) acc += Ps[r * 130 + c] * Wb[c * 12 + h];
        attn[(size_t)h * NN + m0 + r] = SC_B * (acc + b_b[h]);
    }
}

// ============ logits (qk + bias + point term + mask) + softmax, in place ============
__global__ void attn_kernel(const float* __restrict__ qkv,
                            const float* __restrict__ head_w, const float* __restrict__ mask,
                            float* __restrict__ attn)
{
    __shared__ float qv[16], qpv[12], row[512], red[4];
    __shared__ float sh_hw;
    const int i = blockIdx.x, h = blockIdx.y, t = threadIdx.x;
    if (t < 16) qv[t] = qkv[(size_t)i * DQKV + h * 16 + t];
    if (t < 12) qpv[t] = qkv[(size_t)i * DQKV + 576 + h * 12 + t];
    if (t == 0) sh_hw = 0.5f * HW_SC * log1pf(expf(head_w[h]));
    __syncthreads();
    float mi = mask[i];
    float* arow = attn + ((size_t)h * N + i) * N;
    for (int j = t; j < N; j += 256) {
        const float* kr = qkv + (size_t)j * DQKV + 192 + h * 32;
        float qk = 0.f;
        #pragma unroll
        for (int c = 0; c < 16; ++c) qk += qv[c] * kr[c];
        const float* kp = qkv + (size_t)j * DQKV + 720 + h * 36;
        float d2 = 0.f;
        #pragma unroll
        for (int e = 0; e < 12; ++e) { float df = qpv[e] - kp[e]; d2 += df * df; }
        row[j] = qk * SC_QK + arow[j] - sh_hw * d2 + (mi * mask[j] - 1.0f) * INFV;
    }
    __syncthreads();
    float v = fmaxf(row[t], row[t + 256]);
    for (int off = 32; off; off >>= 1) v = fmaxf(v, __shfl_xor(v, off));
    if ((t & 63) == 0) red[t >> 6] = v;
    __syncthreads();
    float mx = fmaxf(fmaxf(red[0], red[1]), fmaxf(red[2], red[3]));
    __syncthreads();
    float e0 = expf(row[t] - mx), e1 = expf(row[t + 256] - mx);
    float sv = e0 + e1;
    for (int off = 32; off; off >>= 1) sv += __shfl_xor(sv, off);
    if ((t & 63) == 0) red[t >> 6] = sv;
    __syncthreads();
    float inv = 1.0f / (red[0] + red[1] + red[2] + red[3]);
    arow[t] = e0 * inv;
    arow[t + 256] = e1 * inv;
}

// ============ O = A @ [v | vp] per head; o -> cat_bf (bf16), vp part -> opraw f32 ============
__global__ void ov_kernel(const float* __restrict__ attn, const float* __restrict__ qkv,
                          ushort_t* __restrict__ catb, float* __restrict__ opraw)
{
    __shared__ float As[32 * 65];
    __shared__ float Rs[64 * 41];
    const int t = threadIdx.x;
    const int i0 = blockIdx.x * 32, h = blockIdx.y;
    const int r = t >> 3, g = t & 7;
    float acc[5] = {0.f, 0.f, 0.f, 0.f, 0.f};
    for (int jt = 0; jt < 8; ++jt) {
        int j0 = jt * 64;
        for (int idx = t; idx < 2048; idx += 256) {
            int rr = idx >> 6, jj = idx & 63;
            As[rr * 65 + jj] = attn[((size_t)h * N + i0 + rr) * N + j0 + jj];
        }
        for (int idx = t; idx < 2560; idx += 256) {
            int jj = idx / 40, c = idx % 40;
            float vv;
            if (c < 16) vv = qkv[(size_t)(j0 + jj) * DQKV + 192 + h * 32 + 16 + c];
            else        vv = qkv[(size_t)(j0 + jj) * DQKV + 720 + h * 36 + 12 + (c - 16)];
            Rs[jj * 41 + c] = vv;
        }
        __syncthreads();
        for (int jj = 0; jj < 64; ++jj) {
            float av = As[r * 65 + jj];
            #pragma unroll
            for (int c5 = 0; c5 < 5; ++c5) acc[c5] += av * Rs[jj * 41 + g * 5 + c5];
        }
        __syncthreads();
    }
    int i = i0 + r;
    #pragma unroll
    for (int c5 = 0; c5 < 5; ++c5) {
        int c = g * 5 + c5;
        if (c < 16) catb[(size_t)i * DCAT + h * 16 + c] = (ushort_t)f2bf(acc[c5]);
        else        opraw[i * 288 + h * 24 + (c - 16)] = acc[c5];
    }
}

// ============ op finalize: R^T (op - t), norms -> cat_bf ============
__global__ void opfin_kernel(const float* __restrict__ opraw, const float* __restrict__ rot,
                             const float* __restrict__ trans, ushort_t* __restrict__ catb)
{
    int gid = blockIdx.x * 256 + threadIdx.x;
    if (gid >= N * 96) return;
    int i = gid / 96, rem = gid % 96;
    int h = rem >> 3, pv = rem & 7;
    const float* o = opraw + i * 288 + h * 24 + pv * 3;
    const float* T = trans + i * 3;
    const float* R = rot + i * 9;
    float x = o[0] - T[0], y = o[1] - T[1], z = o[2] - T[2];
    float rx = R[0] * x + R[3] * y + R[6] * z;
    float ry = R[1] * x + R[4] * y + R[7] * z;
    float rz = R[2] * x + R[5] * y + R[8] * z;
    float nm = sqrtf(rx * rx + ry * ry + rz * rz + 1e-8f);
    ushort_t* cr = catb + (size_t)i * DCAT;
    cr[192 + h * 24 + pv * 3 + 0] = (ushort_t)f2bf(rx);
    cr[192 + h * 24 + pv * 3 + 1] = (ushort_t)f2bf(ry);
    cr[192 + h * 24 + pv * 3 + 2] = (ushort_t)f2bf(rz);
    cr[480 + h * 8 + pv] = (ushort_t)f2bf(nm);
}

// ============ o_pair[i,h,c] = sum_j a[h,i,j] p[i,j,c] -> cat_bf ============
__global__ void opair_kernel(const float* __restrict__ attn, const float* __restrict__ p,
                             ushort_t* __restrict__ catb)
{
    __shared__ float Ps[4096];
    __shared__ float As[384];
    const int t = threadIdx.x, i = blockIdx.x;
    const int c = t & 127, g = t >> 7;
    float acc[6] = {0.f, 0.f, 0.f, 0.f, 0.f, 0.f};
    for (int jt = 0; jt < 16; ++jt) {
        int j0 = jt * 32;
        for (int idx = t; idx < 4096; idx += 256)
            Ps[idx] = p[((size_t)i * N + j0) * 128 + idx];
        for (int idx = t; idx < 384; idx += 256) {
            int h = idx >> 5, jj = idx & 31;
            As[idx] = attn[((size_t)h * N + i) * N + j0 + jj];
        }
        __syncthreads();
        for (int jj = 0; jj < 32; ++jj) {
            float pv = Ps[jj * 128 + c];
            #pragma unroll
            for (int hh = 0; hh < 6; ++hh)
                acc[hh] += As[(g * 6 + hh) * 32 + jj] * pv;
        }
        __syncthreads();
    }
    #pragma unroll
    for (int hh = 0; hh < 6; ++hh)
        catb[(size_t)i * DCAT + 576 + (g * 6 + hh) * 128 + c] = (ushort_t)f2bf(acc[hh]);
}

// ============ layer norm -> f32 out (opt) + bf16 out (opt) ============
__global__ void ln_kernel(const float* __restrict__ x,
                          const float* __restrict__ g, const float* __restrict__ b,
                          float* __restrict__ outf, ushort_t* __restrict__ outbf)
{
    __shared__ float buf[384];
    __shared__ float red[2], red2[2];
    const int i = blockIdx.x, t = threadIdx.x;
    float s = 0.f, sq = 0.f;
    for (int k = t; k < 384; k += 128) {
        float v = x[(size_t)i * 384 + k];
        buf[k] = v; s += v; sq += v * v;
    }
    for (int off = 32; off; off >>= 1) { s += __shfl_xor(s, off); sq += __shfl_xor(sq, off); }
    if ((t & 63) == 0) { red[t >> 6] = s; red2[t >> 6] = sq; }
    __syncthreads();
    float mean = (red[0] + red[1]) * (1.0f / 384.0f);
    float var = (red2[0] + red2[1]) * (1.0f / 384.0f) - mean * mean;
    float rstd = rsqrtf(var + 1e-5f);
    for (int k = t; k < 384; k += 128) {
        float o = (buf[k] - mean) * rstd * g[k] + b[k];
        if (outf) outf[(size_t)i * 384 + k] = o;
        if (outbf) outbf[(size_t)i * 384 + k] = (ushort_t)f2bf(o);
    }
}

// ============ final: upd, quaternion, rot_new, trans_new ============
__global__ void final_kernel(const float* __restrict__ s2, const float* __restrict__ bb_w,
                             const float* __restrict__ bb_b, const float* __restrict__ rot,
                             const float* __restrict__ trans, float* __restrict__ out_rot,
                             float* __restrict__ out_trans)
{
    int i = blockIdx.x * 64 + threadIdx.x;
    if (i >= N) return;
    float u[6] = {0.f, 0.f, 0.f, 0.f, 0.f, 0.f};
    for (int k = 0; k < 384; ++k) {
        float sv = s2[(size_t)i * 384 + k];
        #pragma unroll
        for (int c = 0; c < 6; ++c) u[c] += sv * bb_w[k * 6 + c];
    }
    #pragma unroll
    for (int c = 0; c < 6; ++c) u[c] += bb_b[c];
    float inq = rsqrtf(1.0f + u[0] * u[0] + u[1] * u[1] + u[2] * u[2]);
    float w = inq, x = u[0] * inq, y = u[1] * inq, z = u[2] * inq;
    float Ru[9];
    Ru[0] = 1.f - 2.f * (y * y + z * z); Ru[1] = 2.f * (x * y - w * z); Ru[2] = 2.f * (x * z + w * y);
    Ru[3] = 2.f * (x * y + w * z); Ru[4] = 1.f - 2.f * (x * x + z * z); Ru[5] = 2.f * (y * z - w * x);
    Ru[6] = 2.f * (x * z - w * y); Ru[7] = 2.f * (y * z + w * x); Ru[8] = 1.f - 2.f * (x * x + y * y);
    const float* R = rot + i * 9;
    #pragma unroll
    for (int a = 0; a < 3; ++a) {
        #pragma unroll
        for (int cc = 0; cc < 3; ++cc)
            out_rot[i * 9 + a * 3 + cc] =
                R[a * 3 + 0] * Ru[0 + cc] + R[a * 3 + 1] * Ru[3 + cc] + R[a * 3 + 2] * Ru[6 + cc];
        out_trans[i * 3 + a] = R[a * 3 + 0] * u[3] + R[a * 3 + 1] * u[4] + R[a * 3 + 2] * u[5]
                               + trans[i * 3 + a];
    }
}

extern "C" void kernel_launch(void* const* d_in, const int* in_sizes, int n_in,
                              void* d_out, int out_size, void* d_ws, size_t ws_size,
                              hipStream_t stream)
{
    const float* s      = (const float*)d_in[0];
    const float* p      = (const float*)d_in[1];
    const float* rot    = (const float*)d_in[2];
    const float* trans  = (const float*)d_in[3];
    const float* mask   = (const float*)d_in[4];
    const float* w_q    = (const float*)d_in[5];
    const float* b_q    = (const float*)d_in[6];
    const float* w_kv   = (const float*)d_in[7];
    const float* b_kv   = (const float*)d_in[8];
    const float* w_qp   = (const float*)d_in[9];
    const float* b_qp   = (const float*)d_in[10];
    const float* w_kvp  = (const float*)d_in[11];
    const float* b_kvp  = (const float*)d_in[12];
    const float* w_b    = (const float*)d_in[13];
    const float* b_b    = (const float*)d_in[14];
    const float* head_w = (const float*)d_in[15];
    const float* w_o    = (const float*)d_in[16];
    const float* b_o    = (const float*)d_in[17];
    const float* ln1_g  = (const float*)d_in[18];
    const float* ln1_b  = (const float*)d_in[19];
    const float* tw1    = (const float*)d_in[20];
    const float* tb1    = (const float*)d_in[21];
    const float* tw2    = (const float*)d_in[22];
    const float* tb2    = (const float*)d_in[23];
    const float* tw3    = (const float*)d_in[24];
    const float* tb3    = (const float*)d_in[25];
    const float* ln2_g  = (const float*)d_in[26];
    const float* ln2_b  = (const float*)d_in[27];
    const float* bb_w   = (const float*)d_in[28];
    const float* bb_b   = (const float*)d_in[29];

    float* ws = (float*)d_ws;
    float*    wqkv  = ws;                               // 512*1152 f32        = 589824
    float*    attn  = wqkv + 589824;                    // 12*512*512 f32      = 3145728 (aliased by parts)
    float*    parts = attn;                             // <=6*512*384 f32     = 1179648 (used before/after attn's live range)
    ushort_t* catb  = (ushort_t*)(attn + 3145728);      // 512*2112 bf16       = 540672 f32-equiv
    float*    opr   = (float*)(catb + 1081344);         // 512*288 f32
    float*    s1p   = opr + 147456;                     // 512*384 f32
    float*    s1    = s1p + 196608;                     // 512*384 f32
    ushort_t* sbf   = (ushort_t*)(s1 + 196608);         // 512*384 bf16
    ushort_t* s1bf  = sbf + 196608;
    ushort_t* h1bf  = s1bf + 196608;
    ushort_t* h2bf  = h1bf + 196608;
    ushort_t* Wtp   = h2bf + 196608;                    // 1152*384 bf16
    ushort_t* Wto   = Wtp + 442368;                     // 384*2112 bf16
    ushort_t* Wt1   = Wto + 811008;                     // 384*384 bf16
    ushort_t* Wt2   = Wt1 + 147456;
    ushort_t* Wt3   = Wt2 + 147456;
    float*    biasp = (float*)(Wt3 + 147456);           // 1152 f32

    float* out_s     = (float*)d_out;
    float* out_rot   = out_s + 196608;
    float* out_trans = out_rot + 4608;

    // ---- weight prep: transpose-convert to bf16 Wt[KOUT][KIN] ----
    tc_kernel<<<dim3(6, 12),  256, 0, stream>>>(w_q,   192, 384, Wtp);
    tc_kernel<<<dim3(12, 12), 256, 0, stream>>>(w_kv,  384, 384, Wtp + (size_t)192 * 384);
    tc_kernel<<<dim3(5, 12),  256, 0, stream>>>(w_qp,  144, 384, Wtp + (size_t)576 * 384);
    tc_kernel<<<dim3(14, 12), 256, 0, stream>>>(w_kvp, 432, 384, Wtp + (size_t)720 * 384);
    tc_kernel<<<dim3(12, 66), 256, 0, stream>>>(w_o,   384, 2112, Wto);
    tc_kernel<<<dim3(12, 12), 256, 0, stream>>>(tw1,   384, 384, Wt1);
    tc_kernel<<<dim3(12, 12), 256, 0, stream>>>(tw2,   384, 384, Wt2);
    tc_kernel<<<dim3(12, 12), 256, 0, stream>>>(tw3,   384, 384, Wt3);
    conv_kernel<<<192, 256, 0, stream>>>(s, sbf, 49152);
    hipMemcpyAsync(biasp,       b_q,  192 * 4, hipMemcpyDeviceToDevice, stream);
    hipMemcpyAsync(biasp + 192, b_kv, 384 * 4, hipMemcpyDeviceToDevice, stream);
    hipMemcpyAsync(biasp + 576, b_qp, 144 * 4, hipMemcpyDeviceToDevice, stream);
    hipMemcpyAsync(biasp + 720, b_kvp, 432 * 4, hipMemcpyDeviceToDevice, stream);

    // ---- fused projection GEMM: [512x384] @ [384x1152] ----
    gemm_bf16<<<dim3(8, 18, 2), 256, 0, stream>>>(sbf, Wtp, parts, 384, 1152, 6);
    reduce_k<<<576, 256, 0, stream>>>(parts, 2, 1152, biasp, nullptr, 0, wqkv, nullptr);
    rotate_pts<<<96, 256, 0, stream>>>(wqkv, rot, trans, 576, 48);
    rotate_pts<<<288, 256, 0, stream>>>(wqkv, rot, trans, 720, 144);

    // ---- attention ----
    bias_kernel<<<NN / 32, 256, 0, stream>>>(p, w_b, b_b, attn);
    attn_kernel<<<dim3(512, 12), 256, 0, stream>>>(wqkv, head_w, mask, attn);
    ov_kernel<<<dim3(16, 12), 256, 0, stream>>>(attn, wqkv, catb, opr);
    opfin_kernel<<<192, 256, 0, stream>>>(opr, rot, trans, catb);
    opair_kernel<<<512, 256, 0, stream>>>(attn, p, catb);

    // ---- output projection + residual + LN (parts reuses attn region; attn dead now) ----
    gemm_bf16<<<dim3(8, 6, 6), 256, 0, stream>>>(catb, Wto, parts, 2112, 384, 11);
    reduce_k<<<192, 256, 0, stream>>>(parts, 6, 384, b_o, s, 0, s1p, nullptr);
    ln_kernel<<<512, 128, 0, stream>>>(s1p, ln1_g, ln1_b, s1, s1bf);

    // ---- transition ----
    gemm_bf16<<<dim3(8, 6, 3), 256, 0, stream>>>(s1bf, Wt1, parts, 384, 384, 4);
    reduce_k<<<192, 256, 0, stream>>>(parts, 3, 384, tb1, nullptr, 1, nullptr, h1bf);
    gemm_bf16<<<dim3(8, 6, 3), 256, 0, stream>>>(h1bf, Wt2, parts, 384, 384, 4);
    reduce_k<<<192, 256, 0, stream>>>(parts, 3, 384, tb2, nullptr, 1, nullptr, h2bf);
    gemm_bf16<<<dim3(8, 6, 3), 256, 0, stream>>>(h2bf, Wt3, parts, 384, 384, 4);
    reduce_k<<<192, 256, 0, stream>>>(parts, 3, 384, tb3, s1, 0, s1p, nullptr);
    ln_kernel<<<512, 128, 0, stream>>>(s1p, ln2_g, ln2_b, out_s, nullptr);

    // ---- rigid update ----
    final_kernel<<<8, 64, 0, stream>>>(out_s, bb_w, bb_b, rot, trans, out_rot, out_trans);
}

// Round 4
// 273.663 us; speedup vs baseline: 2.5649x; 1.4076x over previous
//
#include <hip/hip_runtime.h>
#include <math.h>

#define N 512
#define CS 384
#define CP 128
#define CH 16
#define NH 12
#define NN (N*N)
#define DCAT 2112
#define DQKV 1152
#define INFV 100000.0f

__device__ __constant__ float SC_QK = 0.14433756729740643f; // sqrt(1/48)
#define SC_B  0.57735026918962576f  // sqrt(1/3)
#define HW_SC 0.13608276348795434f  // sqrt(1/54)

typedef __attribute__((ext_vector_type(8))) short bf16x8;
typedef __attribute__((ext_vector_type(4))) float f32x4;
typedef __attribute__((ext_vector_type(4))) short sh4;
typedef unsigned short ushort_t;

__device__ inline short f2bf(float v) {
    unsigned u = __builtin_bit_cast(unsigned, v);
    u += 0x7FFF + ((u >> 16) & 1);   // round-to-nearest-even
    return (short)(u >> 16);
}

__device__ __forceinline__ void gload16(const void* g, void* l) {
    __builtin_amdgcn_global_load_lds(
        (const __attribute__((address_space(1))) unsigned int*)g,
        (__attribute__((address_space(3))) unsigned int*)l,
        16, 0, 0);
}

// ============ merged prep: weight transposes + s conversion + bias concat ============
struct PrepArgs {
    const float* wsrc0; const float* wsrc1; const float* wsrc2; const float* wsrc3;
    const float* wsrc4; const float* wsrc5; const float* wsrc6; const float* wsrc7;
    ushort_t* wdst0; ushort_t* wdst1; ushort_t* wdst2; ushort_t* wdst3;
    ushort_t* wdst4; ushort_t* wdst5; ushort_t* wdst6; ushort_t* wdst7;
    const float* s; ushort_t* sbf;
    const float* bq; const float* bkv; const float* bqp; const float* bkvp;
    float* biasp;
};

__global__ __launch_bounds__(256) void prep_kernel(PrepArgs a)
{
    const int b = blockIdx.x;
    if (b < 1668) {
        const float* src; ushort_t* dst; int begin, nx, Nc, K;
        if      (b < 72)   { src=a.wsrc0; dst=a.wdst0; begin=0;    nx=6;  Nc=192; K=384; }
        else if (b < 216)  { src=a.wsrc1; dst=a.wdst1; begin=72;   nx=12; Nc=384; K=384; }
        else if (b < 276)  { src=a.wsrc2; dst=a.wdst2; begin=216;  nx=5;  Nc=144; K=384; }
        else if (b < 444)  { src=a.wsrc3; dst=a.wdst3; begin=276;  nx=14; Nc=432; K=384; }
        else if (b < 1236) { src=a.wsrc4; dst=a.wdst4; begin=444;  nx=12; Nc=384; K=2112; }
        else if (b < 1380) { src=a.wsrc5; dst=a.wdst5; begin=1236; nx=12; Nc=384; K=384; }
        else if (b < 1524) { src=a.wsrc6; dst=a.wdst6; begin=1380; nx=12; Nc=384; K=384; }
        else               { src=a.wsrc7; dst=a.wdst7; begin=1524; nx=12; Nc=384; K=384; }
        int lb = b - begin;
        int cx = (lb % nx) * 32, ky = (lb / nx) * 32;
        __shared__ float tile[32][33];
        const int tx = threadIdx.x & 31, ty = threadIdx.x >> 5;
        for (int r = ty; r < 32; r += 8) {
            int c = cx + tx;
            tile[r][tx] = (c < Nc) ? src[(size_t)(ky + r) * Nc + c] : 0.f;
        }
        __syncthreads();
        for (int r = ty; r < 32; r += 8) {
            int orow = cx + r;
            if (orow < Nc)
                dst[(size_t)orow * K + ky + tx] = (ushort_t)f2bf(tile[tx][r]);
        }
    } else if (b < 1860) {
        int i4 = (b - 1668) * 256 + threadIdx.x;   // 49152 vec4s
        f32x4 v = *(const f32x4*)(a.s + (size_t)i4 * 4);
        sh4 o;
        o[0] = f2bf(v[0]); o[1] = f2bf(v[1]); o[2] = f2bf(v[2]); o[3] = f2bf(v[3]);
        *(sh4*)(a.sbf + (size_t)i4 * 4) = o;
    } else {
        for (int idx = threadIdx.x; idx < 1152; idx += 256) {
            float v;
            if (idx < 192)      v = a.bq[idx];
            else if (idx < 576) v = a.bkv[idx - 192];
            else if (idx < 720) v = a.bqp[idx - 576];
            else                v = a.bkvp[idx - 720];
            a.biasp[idx] = v;
        }
    }
}

// ============ bf16 MFMA GEMM, 64x64 tile, BK=32, 2-phase pipelined, split-K ============
__global__ __launch_bounds__(256) void gemm_bf16(
    const ushort_t* __restrict__ A, const ushort_t* __restrict__ Bt,
    float* __restrict__ part, int K, int KOUT, int nk)
{
    __shared__ __align__(16) ushort_t As[2][2048];
    __shared__ __align__(16) ushort_t Bs[2][2048];
    const int t = threadIdx.x, w = t >> 6, l = t & 63;
    const int i0 = blockIdx.x * 64, n0 = blockIdx.y * 64, sp = blockIdx.z;
    const int kbase = sp * nk * 32;

    const int srow = w * 16 + (l >> 2);
    const int skb = (l & 3) ^ ((srow >> 1) & 3);
    const ushort_t* aSrc = A + (size_t)(i0 + srow) * K + kbase + skb * 8;
    const ushort_t* bSrc = Bt + (size_t)(n0 + srow) * K + kbase + skb * 8;
    ushort_t* aDst = &As[0][0] + w * 512;
    ushort_t* bDst = &Bs[0][0] + w * 512;

    const int r0 = (w >> 1) * 32, c0 = (w & 1) * 32, lr = l & 15, hk = l >> 4;
    int aOff[2], bOff[2];
    #pragma unroll
    for (int m = 0; m < 2; ++m) {
        int row = r0 + m * 16 + lr;
        aOff[m] = row * 64 + ((hk ^ ((row >> 1) & 3)) << 4);
    }
    #pragma unroll
    for (int n = 0; n < 2; ++n) {
        int row = c0 + n * 16 + lr;
        bOff[n] = row * 64 + ((hk ^ ((row >> 1) & 3)) << 4);
    }

    f32x4 acc[2][2];
    #pragma unroll
    for (int m = 0; m < 2; ++m)
        #pragma unroll
        for (int n = 0; n < 2; ++n) acc[m][n] = (f32x4){0.f, 0.f, 0.f, 0.f};

    gload16(aSrc, aDst);
    gload16(bSrc, bDst);
    __syncthreads();

    int cur = 0;
    for (int it = 0; it < nk; ++it) {
        if (it + 1 < nk) {
            gload16(aSrc + (it + 1) * 32, aDst + (cur ^ 1) * 2048);
            gload16(bSrc + (it + 1) * 32, bDst + (cur ^ 1) * 2048);
        }
        const char* ab = (const char*)&As[cur][0];
        const char* bb = (const char*)&Bs[cur][0];
        bf16x8 a0 = *(const bf16x8*)(ab + aOff[0]);
        bf16x8 a1 = *(const bf16x8*)(ab + aOff[1]);
        bf16x8 b0 = *(const bf16x8*)(bb + bOff[0]);
        bf16x8 b1 = *(const bf16x8*)(bb + bOff[1]);
        acc[0][0] = __builtin_amdgcn_mfma_f32_16x16x32_bf16(a0, b0, acc[0][0], 0, 0, 0);
        acc[0][1] = __builtin_amdgcn_mfma_f32_16x16x32_bf16(a0, b1, acc[0][1], 0, 0, 0);
        acc[1][0] = __builtin_amdgcn_mfma_f32_16x16x32_bf16(a1, b0, acc[1][0], 0, 0, 0);
        acc[1][1] = __builtin_amdgcn_mfma_f32_16x16x32_bf16(a1, b1, acc[1][1], 0, 0, 0);
        __syncthreads();
        cur ^= 1;
    }

    #pragma unroll
    for (int m = 0; m < 2; ++m)
        #pragma unroll
        for (int n = 0; n < 2; ++n) {
            int col = n0 + c0 + n * 16 + lr;
            int rowb = i0 + r0 + m * 16 + (l >> 4) * 4;
            float* pr = part + ((size_t)sp * 512 + rowb) * KOUT + col;
            #pragma unroll
            for (int j = 0; j < 4; ++j)
                pr[(size_t)j * KOUT] = acc[m][n][j];
        }
}

// ============ reduce split-K partials + bias (+resid)(+relu) -> f32 and/or bf16 ============
__global__ void reduce_k(const float* __restrict__ parts, int S, int KOUT,
                         const float* __restrict__ bias, const float* __restrict__ resid,
                         int relu, float* __restrict__ outf, ushort_t* __restrict__ outbf)
{
    int i4 = blockIdx.x * 256 + threadIdx.x;
    int tot = 512 * KOUT / 4;
    if (i4 >= tot) return;
    int idx = i4 * 4, c = idx % KOUT;
    f32x4 v = *(const f32x4*)(bias + c);
    for (int s2 = 0; s2 < S; ++s2)
        v += *(const f32x4*)(parts + (size_t)s2 * 512 * KOUT + idx);
    if (resid) v += *(const f32x4*)(resid + idx);
    if (relu) {
        v[0] = fmaxf(v[0], 0.f); v[1] = fmaxf(v[1], 0.f);
        v[2] = fmaxf(v[2], 0.f); v[3] = fmaxf(v[3], 0.f);
    }
    if (outf) *(f32x4*)(outf + idx) = v;
    if (outbf) {
        sh4 o;
        o[0] = f2bf(v[0]); o[1] = f2bf(v[1]); o[2] = f2bf(v[2]); o[3] = f2bf(v[3]);
        *(sh4*)(outbf + idx) = o;
    }
}

// ============ fused reduce split-K + bias + resid + LayerNorm (KOUT=384) ============
__global__ void reduce_ln(const float* __restrict__ parts, int S,
                          const float* __restrict__ gbias, const float* __restrict__ resid,
                          const float* __restrict__ g, const float* __restrict__ b,
                          float* __restrict__ outf, ushort_t* __restrict__ outbf)
{
    __shared__ float buf[384];
    __shared__ float red[2], red2[2];
    const int i = blockIdx.x, t = threadIdx.x;  // 128 threads
    float s = 0.f, sq = 0.f;
    for (int k = t; k < 384; k += 128) {
        float v = gbias[k] + resid[(size_t)i * 384 + k];
        for (int s2 = 0; s2 < S; ++s2)
            v += parts[((size_t)s2 * 512 + i) * 384 + k];
        buf[k] = v; s += v; sq += v * v;
    }
    for (int off = 32; off; off >>= 1) { s += __shfl_xor(s, off); sq += __shfl_xor(sq, off); }
    if ((t & 63) == 0) { red[t >> 6] = s; red2[t >> 6] = sq; }
    __syncthreads();
    float mean = (red[0] + red[1]) * (1.0f / 384.0f);
    float var = (red2[0] + red2[1]) * (1.0f / 384.0f) - mean * mean;
    float rstd = rsqrtf(var + 1e-5f);
    for (int k = t; k < 384; k += 128) {
        float o = (buf[k] - mean) * rstd * g[k] + b[k];
        if (outf) outf[(size_t)i * 384 + k] = o;
        if (outbf) outbf[(size_t)i * 384 + k] = (ushort_t)f2bf(o);
    }
}

// ============ rotate points in fused qkv buffer: v <- R v + t ============
__global__ void rotate_pts(float* __restrict__ base, const float* __restrict__ rot,
                           const float* __restrict__ trans, int coloff, int P)
{
    int gid = blockIdx.x * 256 + threadIdx.x;
    if (gid >= N * P) return;
    int n = gid / P, pp = gid % P;
    float* v = base + (size_t)n * DQKV + coloff + pp * 3;
    float x = v[0], y = v[1], z = v[2];
    const float* R = rot + n * 9;
    const float* T = trans + n * 3;
    v[0] = R[0] * x + R[1] * y + R[2] * z + T[0];
    v[1] = R[3] * x + R[4] * y + R[5] * z + T[1];
    v[2] = R[6] * x + R[7] * y + R[8] * z + T[2];
}

// ============ bias via MFMA: attn[h][row] = SC_B * (P[row][:] @ w_b[:,h] + b_b[h]) ========
// block: 128 pair-rows; LDS P tile [128][128] bf16 swizzled; w_bT [16][128] bf16 swizzled
__global__ __launch_bounds__(256) void bias_mfma(
    const float* __restrict__ p, const float* __restrict__ w_b,
    const float* __restrict__ b_b, float* __restrict__ attn)
{
    __shared__ __align__(16) ushort_t Ps[128 * 128];
    __shared__ __align__(16) ushort_t Wbs[16 * 128];
    const int t = threadIdx.x;
    const size_t row0 = (size_t)blockIdx.x * 128;

    for (int idx = t; idx < 2048; idx += 256) {
        int h = idx >> 7, c = idx & 127;
        float v = (h < 12) ? w_b[c * 12 + h] : 0.f;
        int byte = h * 256 + ((c * 2) ^ ((h & 7) << 4));
        *(ushort_t*)((char*)Wbs + byte) = (ushort_t)f2bf(v);
    }
    const float* src = p + row0 * 128;
    #pragma unroll
    for (int i = 0; i < 16; ++i) {
        int idx = t * 4 + i * 1024;
        f32x4 v = *(const f32x4*)(src + idx);
        sh4 o;
        o[0] = f2bf(v[0]); o[1] = f2bf(v[1]); o[2] = f2bf(v[2]); o[3] = f2bf(v[3]);
        int j = idx >> 7, c = idx & 127;
        int byte = j * 256 + ((c * 2) ^ ((j & 7) << 4));
        *(sh4*)((char*)Ps + byte) = o;
    }
    __syncthreads();

    const int w = t >> 6, l = t & 63;
    const int jb = w * 32, lr = l & 15, hk = l >> 4;
    f32x4 acc[2];
    acc[0] = (f32x4){0.f, 0.f, 0.f, 0.f};
    acc[1] = (f32x4){0.f, 0.f, 0.f, 0.f};
    #pragma unroll
    for (int ks = 0; ks < 4; ++ks) {
        int kbyte = ks * 64 + hk * 16;
        bf16x8 bfr = *(const bf16x8*)((char*)Wbs + lr * 256 + (kbyte ^ ((lr & 7) << 4)));
        #pragma unroll
        for (int m = 0; m < 2; ++m) {
            int j = jb + m * 16 + lr;
            bf16x8 afr = *(const bf16x8*)((char*)Ps + j * 256 + (kbyte ^ ((j & 7) << 4)));
            acc[m] = __builtin_amdgcn_mfma_f32_16x16x32_bf16(afr, bfr, acc[m], 0, 0, 0);
        }
    }
    if (lr < 12) {
        float bb = b_b[lr];
        #pragma unroll
        for (int m = 0; m < 2; ++m)
            #pragma unroll
            for (int r = 0; r < 4; ++r) {
                size_t j = row0 + jb + m * 16 + hk * 4 + r;
                attn[(size_t)lr * NN + j] = SC_B * (acc[m][r] + bb);
            }
    }
}

// ============ logits (qk + bias + point term + mask) + softmax, in place ============
__global__ void attn_kernel(const float* __restrict__ qkv,
                            const float* __restrict__ head_w, const float* __restrict__ mask,
                            float* __restrict__ attn)
{
    __shared__ float qv[16], qpv[12], row[512], red[4];
    __shared__ float sh_hw;
    const int i = blockIdx.x, h = blockIdx.y, t = threadIdx.x;
    if (t < 16) qv[t] = qkv[(size_t)i * DQKV + h * 16 + t];
    if (t < 12) qpv[t] = qkv[(size_t)i * DQKV + 576 + h * 12 + t];
    if (t == 0) sh_hw = 0.5f * HW_SC * log1pf(expf(head_w[h]));
    __syncthreads();
    float mi = mask[i];
    float* arow = attn + ((size_t)h * N + i) * N;
    for (int j = t; j < N; j += 256) {
        const float* kr = qkv + (size_t)j * DQKV + 192 + h * 32;
        float qk = 0.f;
        #pragma unroll
        for (int c = 0; c < 16; ++c) qk += qv[c] * kr[c];
        const float* kp = qkv + (size_t)j * DQKV + 720 + h * 36;
        float d2 = 0.f;
        #pragma unroll
        for (int e = 0; e < 12; ++e) { float df = qpv[e] - kp[e]; d2 += df * df; }
        row[j] = qk * SC_QK + arow[j] - sh_hw * d2 + (mi * mask[j] - 1.0f) * INFV;
    }
    __syncthreads();
    float v = fmaxf(row[t], row[t + 256]);
    for (int off = 32; off; off >>= 1) v = fmaxf(v, __shfl_xor(v, off));
    if ((t & 63) == 0) red[t >> 6] = v;
    __syncthreads();
    float mx = fmaxf(fmaxf(red[0], red[1]), fmaxf(red[2], red[3]));
    __syncthreads();
    float e0 = expf(row[t] - mx), e1 = expf(row[t + 256] - mx);
    float sv = e0 + e1;
    for (int off = 32; off; off >>= 1) sv += __shfl_xor(sv, off);
    if ((t & 63) == 0) red[t >> 6] = sv;
    __syncthreads();
    float inv = 1.0f / (red[0] + red[1] + red[2] + red[3]);
    arow[t] = e0 * inv;
    arow[t + 256] = e1 * inv;
}

// ============ O = A @ [v | vp] per head; o -> cat_bf (bf16), vp part -> opraw f32 ============
__global__ void ov_kernel(const float* __restrict__ attn, const float* __restrict__ qkv,
                          ushort_t* __restrict__ catb, float* __restrict__ opraw)
{
    __shared__ float As[32 * 65];
    __shared__ float Rs[64 * 41];
    const int t = threadIdx.x;
    const int i0 = blockIdx.x * 32, h = blockIdx.y;
    const int r = t >> 3, g = t & 7;
    float acc[5] = {0.f, 0.f, 0.f, 0.f, 0.f};
    for (int jt = 0; jt < 8; ++jt) {
        int j0 = jt * 64;
        for (int idx = t; idx < 2048; idx += 256) {
            int rr = idx >> 6, jj = idx & 63;
            As[rr * 65 + jj] = attn[((size_t)h * N + i0 + rr) * N + j0 + jj];
        }
        for (int idx = t; idx < 2560; idx += 256) {
            int jj = idx / 40, c = idx % 40;
            float vv;
            if (c < 16) vv = qkv[(size_t)(j0 + jj) * DQKV + 192 + h * 32 + 16 + c];
            else        vv = qkv[(size_t)(j0 + jj) * DQKV + 720 + h * 36 + 12 + (c - 16)];
            Rs[jj * 41 + c] = vv;
        }
        __syncthreads();
        for (int jj = 0; jj < 64; ++jj) {
            float av = As[r * 65 + jj];
            #pragma unroll
            for (int c5 = 0; c5 < 5; ++c5) acc[c5] += av * Rs[jj * 41 + g * 5 + c5];
        }
        __syncthreads();
    }
    int i = i0 + r;
    #pragma unroll
    for (int c5 = 0; c5 < 5; ++c5) {
        int c = g * 5 + c5;
        if (c < 16) catb[(size_t)i * DCAT + h * 16 + c] = (ushort_t)f2bf(acc[c5]);
        else        opraw[i * 288 + h * 24 + (c - 16)] = acc[c5];
    }
}

// ============ op finalize: R^T (op - t), norms -> cat_bf ============
__global__ void opfin_kernel(const float* __restrict__ opraw, const float* __restrict__ rot,
                             const float* __restrict__ trans, ushort_t* __restrict__ catb)
{
    int gid = blockIdx.x * 256 + threadIdx.x;
    if (gid >= N * 96) return;
    int i = gid / 96, rem = gid % 96;
    int h = rem >> 3, pv = rem & 7;
    const float* o = opraw + i * 288 + h * 24 + pv * 3;
    const float* T = trans + i * 3;
    const float* R = rot + i * 9;
    float x = o[0] - T[0], y = o[1] - T[1], z = o[2] - T[2];
    float rx = R[0] * x + R[3] * y + R[6] * z;
    float ry = R[1] * x + R[4] * y + R[7] * z;
    float rz = R[2] * x + R[5] * y + R[8] * z;
    float nm = sqrtf(rx * rx + ry * ry + rz * rz + 1e-8f);
    ushort_t* cr = catb + (size_t)i * DCAT;
    cr[192 + h * 24 + pv * 3 + 0] = (ushort_t)f2bf(rx);
    cr[192 + h * 24 + pv * 3 + 1] = (ushort_t)f2bf(ry);
    cr[192 + h * 24 + pv * 3 + 2] = (ushort_t)f2bf(rz);
    cr[480 + h * 8 + pv] = (ushort_t)f2bf(nm);
}

// ============ o_pair via MFMA: O[h][c] = sum_j A[h][j] P[j][c], one block per i ============
// A_i staged [16][512] bf16 (swz (h&7)<<4); P^T staged per 64-j tile as [128 c][64 j] bf16
// (swz ((c>>2)&7)<<4); register prefetch of next p tile.
__global__ __launch_bounds__(256) void opair_mfma(
    const float* __restrict__ attn, const float* __restrict__ p,
    ushort_t* __restrict__ catb)
{
    __shared__ __align__(16) ushort_t As2[16 * 512];
    __shared__ __align__(16) ushort_t Pt[128 * 64];
    const int t = threadIdx.x, i = blockIdx.x;
    const int w = t >> 6, l = t & 63;
    const int lr = l & 15, hk = l >> 4;

    // stage A_i (12x512 f32 -> [16][512] bf16, rows 12..15 zero)
    #pragma unroll
    for (int ii = 0; ii < 8; ++ii) {
        int idx = t * 4 + ii * 1024;
        int h = idx >> 9, j = idx & 511;
        f32x4 v = (h < 12) ? *(const f32x4*)(attn + (size_t)h * NN + (size_t)i * N + j)
                           : (f32x4){0.f, 0.f, 0.f, 0.f};
        sh4 o;
        o[0] = f2bf(v[0]); o[1] = f2bf(v[1]); o[2] = f2bf(v[2]); o[3] = f2bf(v[3]);
        int byte = h * 1024 + ((j * 2) ^ ((h & 7) << 4));
        *(sh4*)((char*)As2 + byte) = o;
    }

    const float* psrc = p + (size_t)i * 65536;
    f32x4 pre[8];
    #pragma unroll
    for (int ii = 0; ii < 8; ++ii)
        pre[ii] = *(const f32x4*)(psrc + t * 4 + ii * 1024);

    f32x4 acc[2];
    acc[0] = (f32x4){0.f, 0.f, 0.f, 0.f};
    acc[1] = (f32x4){0.f, 0.f, 0.f, 0.f};

    __syncthreads();   // As2 ready

    for (int tile = 0; tile < 8; ++tile) {
        // write current tile's P^T from regs
        #pragma unroll
        for (int ii = 0; ii < 8; ++ii) {
            int idx = t * 4 + ii * 1024;
            int j = idx >> 7, c0 = idx & 127;
            #pragma unroll
            for (int e = 0; e < 4; ++e) {
                int c = c0 + e;
                int byte = c * 128 + ((j * 2) ^ ((((c >> 2) & 7)) << 4));
                *(ushort_t*)((char*)Pt + byte) = (ushort_t)f2bf(pre[ii][e]);
            }
        }
        // prefetch next tile
        if (tile < 7) {
            #pragma unroll
            for (int ii = 0; ii < 8; ++ii)
                pre[ii] = *(const f32x4*)(psrc + (tile + 1) * 8192 + t * 4 + ii * 1024);
        }
        __syncthreads();
        // MFMA: wave owns cols w*32..w*32+31 (2 n-frags); K=64 in 2 steps
        #pragma unroll
        for (int ks = 0; ks < 2; ++ks) {
            int kbyte = ks * 64 + hk * 16;
            bf16x8 afr = *(const bf16x8*)((char*)As2 + lr * 1024 +
                             ((tile * 128 + kbyte) ^ ((lr & 7) << 4)));
            #pragma unroll
            for (int n = 0; n < 2; ++n) {
                int c = w * 32 + n * 16 + lr;
                bf16x8 bfr = *(const bf16x8*)((char*)Pt + c * 128 +
                                 (kbyte ^ ((((c >> 2) & 7)) << 4)));
                acc[n] = __builtin_amdgcn_mfma_f32_16x16x32_bf16(afr, bfr, acc[n], 0, 0, 0);
            }
        }
        __syncthreads();
    }
    // epilogue: lane: col c = w*32 + n*16 + lr; row h = hk*4 + r
    #pragma unroll
    for (int n = 0; n < 2; ++n) {
        int c = w * 32 + n * 16 + lr;
        #pragma unroll
        for (int r = 0; r < 4; ++r) {
            int h = hk * 4 + r;
            if (h < 12)
                catb[(size_t)i * DCAT + 576 + h * 128 + c] = (ushort_t)f2bf(acc[n][r]);
        }
    }
}

// ============ final: upd, quaternion, rot_new, trans_new ============
__global__ void final_kernel(const float* __restrict__ s2, const float* __restrict__ bb_w,
                             const float* __restrict__ bb_b, const float* __restrict__ rot,
                             const float* __restrict__ trans, float* __restrict__ out_rot,
                             float* __restrict__ out_trans)
{
    int i = blockIdx.x * 64 + threadIdx.x;
    if (i >= N) return;
    float u[6] = {0.f, 0.f, 0.f, 0.f, 0.f, 0.f};
    for (int k = 0; k < 384; ++k) {
        float sv = s2[(size_t)i * 384 + k];
        #pragma unroll
        for (int c = 0; c < 6; ++c) u[c] += sv * bb_w[k * 6 + c];
    }
    #pragma unroll
    for (int c = 0; c < 6; ++c) u[c] += bb_b[c];
    float inq = rsqrtf(1.0f + u[0] * u[0] + u[1] * u[1] + u[2] * u[2]);
    float w = inq, x = u[0] * inq, y = u[1] * inq, z = u[2] * inq;
    float Ru[9];
    Ru[0] = 1.f - 2.f * (y * y + z * z); Ru[1] = 2.f * (x * y - w * z); Ru[2] = 2.f * (x * z + w * y);
    Ru[3] = 2.f * (x * y + w * z); Ru[4] = 1.f - 2.f * (x * x + z * z); Ru[5] = 2.f * (y * z - w * x);
    Ru[6] = 2.f * (x * z - w * y); Ru[7] = 2.f * (y * z + w * x); Ru[8] = 1.f - 2.f * (x * x + y * y);
    const float* R = rot + i * 9;
    #pragma unroll
    for (int a = 0; a < 3; ++a) {
        #pragma unroll
        for (int cc = 0; cc < 3; ++cc)
            out_rot[i * 9 + a * 3 + cc] =
                R[a * 3 + 0] * Ru[0 + cc] + R[a * 3 + 1] * Ru[3 + cc] + R[a * 3 + 2] * Ru[6 + cc];
        out_trans[i * 3 + a] = R[a * 3 + 0] * u[3] + R[a * 3 + 1] * u[4] + R[a * 3 + 2] * u[5]
                               + trans[i * 3 + a];
    }
}

extern "C" void kernel_launch(void* const* d_in, const int* in_sizes, int n_in,
                              void* d_out, int out_size, void* d_ws, size_t ws_size,
                              hipStream_t stream)
{
    const float* s      = (const float*)d_in[0];
    const float* p      = (const float*)d_in[1];
    const float* rot    = (const float*)d_in[2];
    const float* trans  = (const float*)d_in[3];
    const float* mask   = (const float*)d_in[4];
    const float* w_q    = (const float*)d_in[5];
    const float* b_q    = (const float*)d_in[6];
    const float* w_kv   = (const float*)d_in[7];
    const float* b_kv   = (const float*)d_in[8];
    const float* w_qp   = (const float*)d_in[9];
    const float* b_qp   = (const float*)d_in[10];
    const float* w_kvp  = (const float*)d_in[11];
    const float* b_kvp  = (const float*)d_in[12];
    const float* w_b    = (const float*)d_in[13];
    const float* b_b    = (const float*)d_in[14];
    const float* head_w = (const float*)d_in[15];
    const float* w_o    = (const float*)d_in[16];
    const float* b_o    = (const float*)d_in[17];
    const float* ln1_g  = (const float*)d_in[18];
    const float* ln1_b  = (const float*)d_in[19];
    const float* tw1    = (const float*)d_in[20];
    const float* tb1    = (const float*)d_in[21];
    const float* tw2    = (const float*)d_in[22];
    const float* tb2    = (const float*)d_in[23];
    const float* tw3    = (const float*)d_in[24];
    const float* tb3    = (const float*)d_in[25];
    const float* ln2_g  = (const float*)d_in[26];
    const float* ln2_b  = (const float*)d_in[27];
    const float* bb_w   = (const float*)d_in[28];
    const float* bb_b   = (const float*)d_in[29];

    float* ws = (float*)d_ws;
    float*    wqkv  = ws;                               // 512*1152 f32
    float*    attn  = wqkv + 589824;                    // 12*512*512 f32 (aliased by parts)
    float*    parts = attn;                             // <=6*512*384 f32
    ushort_t* catb  = (ushort_t*)(attn + 3145728);      // 512*2112 bf16
    float*    opr   = (float*)(catb + 1081344);         // 512*288 f32
    float*    s1p   = opr + 147456;                     // (spare)
    float*    s1    = s1p + 196608;                     // 512*384 f32
    ushort_t* sbf   = (ushort_t*)(s1 + 196608);
    ushort_t* s1bf  = sbf + 196608;
    ushort_t* h1bf  = s1bf + 196608;
    ushort_t* h2bf  = h1bf + 196608;
    ushort_t* Wtp   = h2bf + 196608;                    // 1152*384 bf16
    ushort_t* Wto   = Wtp + 442368;                     // 384*2112 bf16
    ushort_t* Wt1   = Wto + 811008;
    ushort_t* Wt2   = Wt1 + 147456;
    ushort_t* Wt3   = Wt2 + 147456;
    float*    biasp = (float*)(Wt3 + 147456);           // 1152 f32

    float* out_s     = (float*)d_out;
    float* out_rot   = out_s + 196608;
    float* out_trans = out_rot + 4608;

    // ---- merged prep ----
    PrepArgs pa;
    pa.wsrc0 = w_q;  pa.wdst0 = Wtp;
    pa.wsrc1 = w_kv; pa.wdst1 = Wtp + (size_t)192 * 384;
    pa.wsrc2 = w_qp; pa.wdst2 = Wtp + (size_t)576 * 384;
    pa.wsrc3 = w_kvp; pa.wdst3 = Wtp + (size_t)720 * 384;
    pa.wsrc4 = w_o;  pa.wdst4 = Wto;
    pa.wsrc5 = tw1;  pa.wdst5 = Wt1;
    pa.wsrc6 = tw2;  pa.wdst6 = Wt2;
    pa.wsrc7 = tw3;  pa.wdst7 = Wt3;
    pa.s = s; pa.sbf = sbf;
    pa.bq = b_q; pa.bkv = b_kv; pa.bqp = b_qp; pa.bkvp = b_kvp;
    pa.biasp = biasp;
    prep_kernel<<<1861, 256, 0, stream>>>(pa);

    // ---- fused projection GEMM ----
    gemm_bf16<<<dim3(8, 18, 2), 256, 0, stream>>>(sbf, Wtp, parts, 384, 1152, 6);
    reduce_k<<<576, 256, 0, stream>>>(parts, 2, 1152, biasp, nullptr, 0, wqkv, nullptr);
    rotate_pts<<<96, 256, 0, stream>>>(wqkv, rot, trans, 576, 48);
    rotate_pts<<<288, 256, 0, stream>>>(wqkv, rot, trans, 720, 144);

    // ---- attention ----
    bias_mfma<<<2048, 256, 0, stream>>>(p, w_b, b_b, attn);
    attn_kernel<<<dim3(512, 12), 256, 0, stream>>>(wqkv, head_w, mask, attn);
    ov_kernel<<<dim3(16, 12), 256, 0, stream>>>(attn, wqkv, catb, opr);
    opfin_kernel<<<192, 256, 0, stream>>>(opr, rot, trans, catb);
    opair_mfma<<<512, 256, 0, stream>>>(attn, p, catb);

    // ---- output projection + residual + LN1 (parts aliases attn; attn dead now) ----
    gemm_bf16<<<dim3(8, 6, 6), 256, 0, stream>>>(catb, Wto, parts, 2112, 384, 11);
    reduce_ln<<<512, 128, 0, stream>>>(parts, 6, b_o, s, ln1_g, ln1_b, s1, s1bf);

    // ---- transition ----
    gemm_bf16<<<dim3(8, 6, 3), 256, 0, stream>>>(s1bf, Wt1, parts, 384, 384, 4);
    reduce_k<<<192, 256, 0, stream>>>(parts, 3, 384, tb1, nullptr, 1, nullptr, h1bf);
    gemm_bf16<<<dim3(8, 6, 3), 256, 0, stream>>>(h1bf, Wt2, parts, 384, 384, 4);
    reduce_k<<<192, 256, 0, stream>>>(parts, 3, 384, tb2, nullptr, 1, nullptr, h2bf);
    gemm_bf16<<<dim3(8, 6, 3), 256, 0, stream>>>(h2bf, Wt3, parts, 384, 384, 4);
    reduce_ln<<<512, 128, 0, stream>>>(parts, 3, tb3, s1, ln2_g, ln2_b, out_s, nullptr);

    // ---- rigid update ----
    final_kernel<<<8, 64, 0, stream>>>(out_s, bb_w, bb_b, rot, trans, out_rot, out_trans);
}

// Round 5
// 166.245 us; speedup vs baseline: 4.2221x; 1.6461x over previous
//
#include <hip/hip_runtime.h>
#include <math.h>

#define N 512
#define CS 384
#define CP 128
#define CH 16
#define NH 12
#define NN (N*N)
#define DCAT 2112
#define DQKV 1152
#define INFV 100000.0f

__device__ __constant__ float SC_QK = 0.14433756729740643f; // sqrt(1/48)
#define SC_B  0.57735026918962576f  // sqrt(1/3)
#define HW_SC 0.13608276348795434f  // sqrt(1/54)

typedef __attribute__((ext_vector_type(8))) short bf16x8;
typedef __attribute__((ext_vector_type(4))) float f32x4;
typedef __attribute__((ext_vector_type(4))) short sh4;
typedef unsigned short ushort_t;

__device__ inline short f2bf(float v) {
    unsigned u = __builtin_bit_cast(unsigned, v);
    u += 0x7FFF + ((u >> 16) & 1);   // round-to-nearest-even
    return (short)(u >> 16);
}
__device__ inline float bf2f(ushort_t u) {
    unsigned x = ((unsigned)u) << 16;
    return __builtin_bit_cast(float, x);
}

__device__ __forceinline__ void gload16(const void* g, void* l) {
    __builtin_amdgcn_global_load_lds(
        (const __attribute__((address_space(1))) unsigned int*)g,
        (__attribute__((address_space(3))) unsigned int*)l,
        16, 0, 0);
}

// ============ merged prep: weight transposes + s conversion + bias concat ============
struct PrepArgs {
    const float* wsrc0; const float* wsrc1; const float* wsrc2; const float* wsrc3;
    const float* wsrc4; const float* wsrc5; const float* wsrc6; const float* wsrc7;
    ushort_t* wdst0; ushort_t* wdst1; ushort_t* wdst2; ushort_t* wdst3;
    ushort_t* wdst4; ushort_t* wdst5; ushort_t* wdst6; ushort_t* wdst7;
    const float* s; ushort_t* sbf;
    const float* bq; const float* bkv; const float* bqp; const float* bkvp;
    float* biasp;
};

__global__ __launch_bounds__(256) void prep_kernel(PrepArgs a)
{
    const int b = blockIdx.x;
    if (b < 1668) {
        const float* src; ushort_t* dst; int begin, nx, Nc, K;
        if      (b < 72)   { src=a.wsrc0; dst=a.wdst0; begin=0;    nx=6;  Nc=192; K=384; }
        else if (b < 216)  { src=a.wsrc1; dst=a.wdst1; begin=72;   nx=12; Nc=384; K=384; }
        else if (b < 276)  { src=a.wsrc2; dst=a.wdst2; begin=216;  nx=5;  Nc=144; K=384; }
        else if (b < 444)  { src=a.wsrc3; dst=a.wdst3; begin=276;  nx=14; Nc=432; K=384; }
        else if (b < 1236) { src=a.wsrc4; dst=a.wdst4; begin=444;  nx=12; Nc=384; K=2112; }
        else if (b < 1380) { src=a.wsrc5; dst=a.wdst5; begin=1236; nx=12; Nc=384; K=384; }
        else if (b < 1524) { src=a.wsrc6; dst=a.wdst6; begin=1380; nx=12; Nc=384; K=384; }
        else               { src=a.wsrc7; dst=a.wdst7; begin=1524; nx=12; Nc=384; K=384; }
        int lb = b - begin;
        int cx = (lb % nx) * 32, ky = (lb / nx) * 32;
        __shared__ float tile[32][33];
        const int tx = threadIdx.x & 31, ty = threadIdx.x >> 5;
        for (int r = ty; r < 32; r += 8) {
            int c = cx + tx;
            tile[r][tx] = (c < Nc) ? src[(size_t)(ky + r) * Nc + c] : 0.f;
        }
        __syncthreads();
        for (int r = ty; r < 32; r += 8) {
            int orow = cx + r;
            if (orow < Nc)
                dst[(size_t)orow * K + ky + tx] = (ushort_t)f2bf(tile[tx][r]);
        }
    } else if (b < 1860) {
        int i4 = (b - 1668) * 256 + threadIdx.x;   // 49152 vec4s
        f32x4 v = *(const f32x4*)(a.s + (size_t)i4 * 4);
        sh4 o;
        o[0] = f2bf(v[0]); o[1] = f2bf(v[1]); o[2] = f2bf(v[2]); o[3] = f2bf(v[3]);
        *(sh4*)(a.sbf + (size_t)i4 * 4) = o;
    } else {
        for (int idx = threadIdx.x; idx < 1152; idx += 256) {
            float v;
            if (idx < 192)      v = a.bq[idx];
            else if (idx < 576) v = a.bkv[idx - 192];
            else if (idx < 720) v = a.bqp[idx - 576];
            else                v = a.bkvp[idx - 720];
            a.biasp[idx] = v;
        }
    }
}

// ============ bf16 MFMA GEMM, 64x64 tile, BK=32, 2-phase pipelined, split-K ============
__global__ __launch_bounds__(256) void gemm_bf16(
    const ushort_t* __restrict__ A, const ushort_t* __restrict__ Bt,
    float* __restrict__ part, int K, int KOUT, int nk)
{
    __shared__ __align__(16) ushort_t As[2][2048];
    __shared__ __align__(16) ushort_t Bs[2][2048];
    const int t = threadIdx.x, w = t >> 6, l = t & 63;
    const int i0 = blockIdx.x * 64, n0 = blockIdx.y * 64, sp = blockIdx.z;
    const int kbase = sp * nk * 32;

    const int srow = w * 16 + (l >> 2);
    const int skb = (l & 3) ^ ((srow >> 1) & 3);
    const ushort_t* aSrc = A + (size_t)(i0 + srow) * K + kbase + skb * 8;
    const ushort_t* bSrc = Bt + (size_t)(n0 + srow) * K + kbase + skb * 8;
    ushort_t* aDst = &As[0][0] + w * 512;
    ushort_t* bDst = &Bs[0][0] + w * 512;

    const int r0 = (w >> 1) * 32, c0 = (w & 1) * 32, lr = l & 15, hk = l >> 4;
    int aOff[2], bOff[2];
    #pragma unroll
    for (int m = 0; m < 2; ++m) {
        int row = r0 + m * 16 + lr;
        aOff[m] = row * 64 + ((hk ^ ((row >> 1) & 3)) << 4);
    }
    #pragma unroll
    for (int n = 0; n < 2; ++n) {
        int row = c0 + n * 16 + lr;
        bOff[n] = row * 64 + ((hk ^ ((row >> 1) & 3)) << 4);
    }

    f32x4 acc[2][2];
    #pragma unroll
    for (int m = 0; m < 2; ++m)
        #pragma unroll
        for (int n = 0; n < 2; ++n) acc[m][n] = (f32x4){0.f, 0.f, 0.f, 0.f};

    gload16(aSrc, aDst);
    gload16(bSrc, bDst);
    __syncthreads();

    int cur = 0;
    for (int it = 0; it < nk; ++it) {
        if (it + 1 < nk) {
            gload16(aSrc + (it + 1) * 32, aDst + (cur ^ 1) * 2048);
            gload16(bSrc + (it + 1) * 32, bDst + (cur ^ 1) * 2048);
        }
        const char* ab = (const char*)&As[cur][0];
        const char* bb = (const char*)&Bs[cur][0];
        bf16x8 a0 = *(const bf16x8*)(ab + aOff[0]);
        bf16x8 a1 = *(const bf16x8*)(ab + aOff[1]);
        bf16x8 b0 = *(const bf16x8*)(bb + bOff[0]);
        bf16x8 b1 = *(const bf16x8*)(bb + bOff[1]);
        acc[0][0] = __builtin_amdgcn_mfma_f32_16x16x32_bf16(a0, b0, acc[0][0], 0, 0, 0);
        acc[0][1] = __builtin_amdgcn_mfma_f32_16x16x32_bf16(a0, b1, acc[0][1], 0, 0, 0);
        acc[1][0] = __builtin_amdgcn_mfma_f32_16x16x32_bf16(a1, b0, acc[1][0], 0, 0, 0);
        acc[1][1] = __builtin_amdgcn_mfma_f32_16x16x32_bf16(a1, b1, acc[1][1], 0, 0, 0);
        __syncthreads();
        cur ^= 1;
    }

    #pragma unroll
    for (int m = 0; m < 2; ++m)
        #pragma unroll
        for (int n = 0; n < 2; ++n) {
            int col = n0 + c0 + n * 16 + lr;
            int rowb = i0 + r0 + m * 16 + (l >> 4) * 4;
            float* pr = part + ((size_t)sp * 512 + rowb) * KOUT + col;
            #pragma unroll
            for (int j = 0; j < 4; ++j)
                pr[(size_t)j * KOUT] = acc[m][n][j];
        }
}

// ============ reduce split-K partials + bias (+resid)(+relu) -> f32 and/or bf16 ============
__global__ void reduce_k(const float* __restrict__ parts, int S, int KOUT,
                         const float* __restrict__ bias, const float* __restrict__ resid,
                         int relu, float* __restrict__ outf, ushort_t* __restrict__ outbf)
{
    int i4 = blockIdx.x * 256 + threadIdx.x;
    int tot = 512 * KOUT / 4;
    if (i4 >= tot) return;
    int idx = i4 * 4, c = idx % KOUT;
    f32x4 v = *(const f32x4*)(bias + c);
    for (int s2 = 0; s2 < S; ++s2)
        v += *(const f32x4*)(parts + (size_t)s2 * 512 * KOUT + idx);
    if (resid) v += *(const f32x4*)(resid + idx);
    if (relu) {
        v[0] = fmaxf(v[0], 0.f); v[1] = fmaxf(v[1], 0.f);
        v[2] = fmaxf(v[2], 0.f); v[3] = fmaxf(v[3], 0.f);
    }
    if (outf) *(f32x4*)(outf + idx) = v;
    if (outbf) {
        sh4 o;
        o[0] = f2bf(v[0]); o[1] = f2bf(v[1]); o[2] = f2bf(v[2]); o[3] = f2bf(v[3]);
        *(sh4*)(outbf + idx) = o;
    }
}

// ============ fused reduce split-K + bias + resid + LayerNorm (KOUT=384) ============
__global__ void reduce_ln(const float* __restrict__ parts, int S,
                          const float* __restrict__ gbias, const float* __restrict__ resid,
                          const float* __restrict__ g, const float* __restrict__ b,
                          float* __restrict__ outf, ushort_t* __restrict__ outbf)
{
    __shared__ float buf[384];
    __shared__ float red[2], red2[2];
    const int i = blockIdx.x, t = threadIdx.x;  // 128 threads
    float s = 0.f, sq = 0.f;
    for (int k = t; k < 384; k += 128) {
        float v = gbias[k] + resid[(size_t)i * 384 + k];
        for (int s2 = 0; s2 < S; ++s2)
            v += parts[((size_t)s2 * 512 + i) * 384 + k];
        buf[k] = v; s += v; sq += v * v;
    }
    for (int off = 32; off; off >>= 1) { s += __shfl_xor(s, off); sq += __shfl_xor(sq, off); }
    if ((t & 63) == 0) { red[t >> 6] = s; red2[t >> 6] = sq; }
    __syncthreads();
    float mean = (red[0] + red[1]) * (1.0f / 384.0f);
    float var = (red2[0] + red2[1]) * (1.0f / 384.0f) - mean * mean;
    float rstd = rsqrtf(var + 1e-5f);
    for (int k = t; k < 384; k += 128) {
        float o = (buf[k] - mean) * rstd * g[k] + b[k];
        if (outf) outf[(size_t)i * 384 + k] = o;
        if (outbf) outbf[(size_t)i * 384 + k] = (ushort_t)f2bf(o);
    }
}

// ============ rotate points in fused qkv buffer: v <- R v + t ============
__global__ void rotate_pts(float* __restrict__ base, const float* __restrict__ rot,
                           const float* __restrict__ trans, int coloff, int P)
{
    int gid = blockIdx.x * 256 + threadIdx.x;
    if (gid >= N * P) return;
    int n = gid / P, pp = gid % P;
    float* v = base + (size_t)n * DQKV + coloff + pp * 3;
    float x = v[0], y = v[1], z = v[2];
    const float* R = rot + n * 9;
    const float* T = trans + n * 3;
    v[0] = R[0] * x + R[1] * y + R[2] * z + T[0];
    v[1] = R[3] * x + R[4] * y + R[5] * z + T[1];
    v[2] = R[6] * x + R[7] * y + R[8] * z + T[2];
}

// ============ qkext: build Qext/Kext [h][512][32] bf16 and Vext [h][48][512] bf16 ============
// Qext = [SC_QK*q(16), hw*qp(12), 1, 0,0,0]
// Kext = [k(16), kp(12), -0.5*hw*|kp|^2 + (mask-1)*INF, 0,0,0]
// Vext[c][j]: c<16 -> v, c<40 -> vp, else 0
__global__ __launch_bounds__(256) void qkext_kernel(
    const float* __restrict__ qkv, const float* __restrict__ head_w,
    const float* __restrict__ mask,
    ushort_t* __restrict__ Qext, ushort_t* __restrict__ Kext, ushort_t* __restrict__ Vext)
{
    const int h = blockIdx.x, q = blockIdx.y, t = threadIdx.x;
    const float hwf = HW_SC * log1pf(expf(head_w[h]));
    const int jl = t & 127, role = t >> 7;
    const int j = q * 128 + jl;
    const float* base = qkv + (size_t)j * DQKV;
    float row[32];
    if (role == 0) {
        #pragma unroll
        for (int c = 0; c < 16; ++c) row[c] = base[192 + h * 32 + c];
        float s2 = 0.f;
        #pragma unroll
        for (int e = 0; e < 12; ++e) {
            float v = base[720 + h * 36 + e];
            row[16 + e] = v; s2 += v * v;
        }
        row[28] = -0.5f * hwf * s2 + (mask[j] - 1.0f) * INFV;
        row[29] = 0.f; row[30] = 0.f; row[31] = 0.f;
        ushort_t* dst = Kext + (size_t)h * 16384 + j * 32;
        #pragma unroll
        for (int g4 = 0; g4 < 8; ++g4) {
            sh4 o;
            o[0] = f2bf(row[g4*4]); o[1] = f2bf(row[g4*4+1]);
            o[2] = f2bf(row[g4*4+2]); o[3] = f2bf(row[g4*4+3]);
            *(sh4*)(dst + g4 * 4) = o;
        }
    } else {
        #pragma unroll
        for (int c = 0; c < 16; ++c) row[c] = SC_QK * base[h * 16 + c];
        #pragma unroll
        for (int e = 0; e < 12; ++e) row[16 + e] = hwf * base[576 + h * 12 + e];
        row[28] = 1.f; row[29] = 0.f; row[30] = 0.f; row[31] = 0.f;
        ushort_t* dst = Qext + (size_t)h * 16384 + j * 32;
        #pragma unroll
        for (int g4 = 0; g4 < 8; ++g4) {
            sh4 o;
            o[0] = f2bf(row[g4*4]); o[1] = f2bf(row[g4*4+1]);
            o[2] = f2bf(row[g4*4+2]); o[3] = f2bf(row[g4*4+3]);
            *(sh4*)(dst + g4 * 4) = o;
        }
    }
    // Vext: 48 c-rows x 128 j per block -> 6144 entries / 256 thr / 4 per write = 6 iters
    for (int it = 0; it < 6; ++it) {
        int idx = t + it * 256;             // [0, 1536)
        int c = idx >> 5, jb = idx & 31;
        int j4 = q * 128 + jb * 4;
        sh4 o;
        if (c < 40) {
            int col = (c < 16) ? (192 + h * 32 + 16 + c) : (720 + h * 36 + 12 + (c - 16));
            #pragma unroll
            for (int e = 0; e < 4; ++e)
                o[e] = f2bf(qkv[(size_t)(j4 + e) * DQKV + col]);
        } else {
            o[0] = 0; o[1] = 0; o[2] = 0; o[3] = 0;
        }
        *(sh4*)(Vext + (size_t)h * 24576 + c * 512 + j4) = o;
    }
}

// ============ bias via MFMA -> bf16 [h][i*N+j] ============
__global__ __launch_bounds__(256) void bias_mfma(
    const float* __restrict__ p, const float* __restrict__ w_b,
    const float* __restrict__ b_b, ushort_t* __restrict__ bias_b)
{
    __shared__ __align__(16) ushort_t Ps[128 * 128];
    __shared__ __align__(16) ushort_t Wbs[16 * 128];
    const int t = threadIdx.x;
    const size_t row0 = (size_t)blockIdx.x * 128;

    for (int idx = t; idx < 2048; idx += 256) {
        int h = idx >> 7, c = idx & 127;
        float v = (h < 12) ? w_b[c * 12 + h] : 0.f;
        int byte = h * 256 + ((c * 2) ^ ((h & 7) << 4));
        *(ushort_t*)((char*)Wbs + byte) = (ushort_t)f2bf(v);
    }
    const float* src = p + row0 * 128;
    #pragma unroll
    for (int i = 0; i < 16; ++i) {
        int idx = t * 4 + i * 1024;
        f32x4 v = *(const f32x4*)(src + idx);
        sh4 o;
        o[0] = f2bf(v[0]); o[1] = f2bf(v[1]); o[2] = f2bf(v[2]); o[3] = f2bf(v[3]);
        int j = idx >> 7, c = idx & 127;
        int byte = j * 256 + ((c * 2) ^ ((j & 7) << 4));
        *(sh4*)((char*)Ps + byte) = o;
    }
    __syncthreads();

    const int w = t >> 6, l = t & 63;
    const int jb = w * 32, lr = l & 15, hk = l >> 4;
    f32x4 acc[2];
    acc[0] = (f32x4){0.f, 0.f, 0.f, 0.f};
    acc[1] = (f32x4){0.f, 0.f, 0.f, 0.f};
    #pragma unroll
    for (int ks = 0; ks < 4; ++ks) {
        int kbyte = ks * 64 + hk * 16;
        bf16x8 bfr = *(const bf16x8*)((char*)Wbs + lr * 256 + (kbyte ^ ((lr & 7) << 4)));
        #pragma unroll
        for (int m = 0; m < 2; ++m) {
            int j = jb + m * 16 + lr;
            bf16x8 afr = *(const bf16x8*)((char*)Ps + j * 256 + (kbyte ^ ((j & 7) << 4)));
            acc[m] = __builtin_amdgcn_mfma_f32_16x16x32_bf16(afr, bfr, acc[m], 0, 0, 0);
        }
    }
    if (lr < 12) {
        float bb = b_b[lr];
        #pragma unroll
        for (int m = 0; m < 2; ++m) {
            size_t j = row0 + jb + m * 16 + hk * 4;
            sh4 o;
            #pragma unroll
            for (int r = 0; r < 4; ++r) o[r] = f2bf(SC_B * (acc[m][r] + bb));
            *(sh4*)(bias_b + (size_t)lr * NN + j) = o;
        }
    }
}

// ============ attn logits via MFMA + softmax -> bf16 weights [h][i][j] ============
// block = (32 i-rows, head); 4 waves each own a 128-wide j window; K=32 (Qext/Kext)
__global__ __launch_bounds__(256) void attn_mfma(
    const ushort_t* __restrict__ Qext, const ushort_t* __restrict__ Kext,
    const ushort_t* __restrict__ bias_b, ushort_t* __restrict__ attn_b)
{
    __shared__ float sc[32 * 516];
    __shared__ float redm[128];
    __shared__ float invr[32];
    const int t = threadIdx.x, w = t >> 6, l = t & 63;
    const int i0 = blockIdx.x * 32, h = blockIdx.y;
    const int lr = l & 15, hk = l >> 4;

    // stage bias tile (bf16 -> f32 LDS)
    #pragma unroll
    for (int it = 0; it < 16; ++it) {
        int elem = (t + it * 256) * 4;
        int i = elem >> 9, j = elem & 511;
        sh4 raw = *(const sh4*)(bias_b + (size_t)h * NN + (size_t)(i0 + i) * 512 + j);
        f32x4 v;
        v[0] = bf2f((ushort_t)raw[0]); v[1] = bf2f((ushort_t)raw[1]);
        v[2] = bf2f((ushort_t)raw[2]); v[3] = bf2f((ushort_t)raw[3]);
        *(f32x4*)(sc + i * 516 + j) = v;
    }
    __syncthreads();

    // MFMA logits: acc[m][n], j-window = w*128
    bf16x8 a0 = *(const bf16x8*)(Qext + (size_t)h * 16384 + (i0 + lr) * 32 + hk * 8);
    bf16x8 a1 = *(const bf16x8*)(Qext + (size_t)h * 16384 + (i0 + 16 + lr) * 32 + hk * 8);
    f32x4 acc[2][8];
    #pragma unroll
    for (int n = 0; n < 8; ++n) {
        bf16x8 b = *(const bf16x8*)(Kext + (size_t)h * 16384 +
                                    (w * 128 + n * 16 + lr) * 32 + hk * 8);
        acc[0][n] = __builtin_amdgcn_mfma_f32_16x16x32_bf16(a0, b, (f32x4){0.f,0.f,0.f,0.f}, 0, 0, 0);
        acc[1][n] = __builtin_amdgcn_mfma_f32_16x16x32_bf16(a1, b, (f32x4){0.f,0.f,0.f,0.f}, 0, 0, 0);
    }

    // add bias, write back to sc, track row maxima
    float rmax[2][4];
    #pragma unroll
    for (int m = 0; m < 2; ++m)
        #pragma unroll
        for (int r = 0; r < 4; ++r) rmax[m][r] = -3.0e38f;
    #pragma unroll
    for (int m = 0; m < 2; ++m)
        #pragma unroll
        for (int n = 0; n < 8; ++n) {
            int col = w * 128 + n * 16 + lr;
            #pragma unroll
            for (int r = 0; r < 4; ++r) {
                int row = m * 16 + hk * 4 + r;
                float v = acc[m][n][r] + sc[row * 516 + col];
                sc[row * 516 + col] = v;
                rmax[m][r] = fmaxf(rmax[m][r], v);
            }
        }
    // reduce max across the 16 lanes sharing each row
    #pragma unroll
    for (int m = 0; m < 2; ++m)
        #pragma unroll
        for (int r = 0; r < 4; ++r) {
            float v = rmax[m][r];
            v = fmaxf(v, __shfl_xor(v, 1));
            v = fmaxf(v, __shfl_xor(v, 2));
            v = fmaxf(v, __shfl_xor(v, 4));
            v = fmaxf(v, __shfl_xor(v, 8));
            if (lr == 0) redm[w * 32 + m * 16 + hk * 4 + r] = v;
        }
    __syncthreads();

    // softmax: 8 threads per row, stride-8 columns
    {
        int row = t >> 3, g = t & 7;
        float mx = fmaxf(fmaxf(redm[row], redm[32 + row]),
                         fmaxf(redm[64 + row], redm[96 + row]));
        float sum = 0.f;
        float* sr = sc + row * 516;
        for (int c = g; c < 512; c += 8) {
            float e = expf(sr[c] - mx);
            sr[c] = e;
            sum += e;
        }
        sum += __shfl_xor(sum, 1);
        sum += __shfl_xor(sum, 2);
        sum += __shfl_xor(sum, 4);
        if (g == 0) invr[row] = 1.0f / sum;
    }
    __syncthreads();

    // write bf16 weights
    #pragma unroll
    for (int it = 0; it < 16; ++it) {
        int elem = (t + it * 256) * 4;
        int i = elem >> 9, j = elem & 511;
        f32x4 v = *(const f32x4*)(sc + i * 516 + j);
        float iv = invr[i];
        sh4 o;
        o[0] = f2bf(v[0] * iv); o[1] = f2bf(v[1] * iv);
        o[2] = f2bf(v[2] * iv); o[3] = f2bf(v[3] * iv);
        *(sh4*)(attn_b + (size_t)h * NN + (size_t)(i0 + i) * 512 + j) = o;
    }
}

// ============ O = A @ [v|vp] via MFMA; 1 wave per (16 i-rows, head) ============
__global__ __launch_bounds__(64) void ov_mfma(
    const ushort_t* __restrict__ attn_b, const ushort_t* __restrict__ Vext,
    ushort_t* __restrict__ catb, float* __restrict__ opr)
{
    const int l = threadIdx.x;
    const int i0 = blockIdx.x * 16, h = blockIdx.y;
    const int lr = l & 15, hk = l >> 4;
    f32x4 acc[3];
    acc[0] = (f32x4){0.f,0.f,0.f,0.f};
    acc[1] = (f32x4){0.f,0.f,0.f,0.f};
    acc[2] = (f32x4){0.f,0.f,0.f,0.f};
    const ushort_t* arow = attn_b + (size_t)h * NN + (size_t)(i0 + lr) * 512 + hk * 8;
    const ushort_t* vbase = Vext + (size_t)h * 24576 + lr * 512 + hk * 8;
    #pragma unroll
    for (int kt = 0; kt < 16; ++kt) {
        bf16x8 af = *(const bf16x8*)(arow + kt * 32);
        #pragma unroll
        for (int n = 0; n < 3; ++n) {
            bf16x8 bf = *(const bf16x8*)(vbase + n * 16 * 512 + kt * 32);
            acc[n] = __builtin_amdgcn_mfma_f32_16x16x32_bf16(af, bf, acc[n], 0, 0, 0);
        }
    }
    #pragma unroll
    for (int n = 0; n < 3; ++n) {
        int c = n * 16 + lr;
        #pragma unroll
        for (int r = 0; r < 4; ++r) {
            int i = i0 + hk * 4 + r;
            if (c < 16)
                catb[(size_t)i * DCAT + h * 16 + c] = (ushort_t)f2bf(acc[n][r]);
            else if (c < 40)
                opr[(size_t)i * 288 + h * 24 + (c - 16)] = acc[n][r];
        }
    }
}

// ============ op finalize: R^T (op - t), norms -> cat_bf ============
__global__ void opfin_kernel(const float* __restrict__ opraw, const float* __restrict__ rot,
                             const float* __restrict__ trans, ushort_t* __restrict__ catb)
{
    int gid = blockIdx.x * 256 + threadIdx.x;
    if (gid >= N * 96) return;
    int i = gid / 96, rem = gid % 96;
    int h = rem >> 3, pv = rem & 7;
    const float* o = opraw + i * 288 + h * 24 + pv * 3;
    const float* T = trans + i * 3;
    const float* R = rot + i * 9;
    float x = o[0] - T[0], y = o[1] - T[1], z = o[2] - T[2];
    float rx = R[0] * x + R[3] * y + R[6] * z;
    float ry = R[1] * x + R[4] * y + R[7] * z;
    float rz = R[2] * x + R[5] * y + R[8] * z;
    float nm = sqrtf(rx * rx + ry * ry + rz * rz + 1e-8f);
    ushort_t* cr = catb + (size_t)i * DCAT;
    cr[192 + h * 24 + pv * 3 + 0] = (ushort_t)f2bf(rx);
    cr[192 + h * 24 + pv * 3 + 1] = (ushort_t)f2bf(ry);
    cr[192 + h * 24 + pv * 3 + 2] = (ushort_t)f2bf(rz);
    cr[480 + h * 8 + pv] = (ushort_t)f2bf(nm);
}

// ============ o_pair via MFMA: O[h][c] = sum_j A[h][j] P[j][c], one block per i ============
__global__ __launch_bounds__(256) void opair_mfma(
    const ushort_t* __restrict__ attn_b, const float* __restrict__ p,
    ushort_t* __restrict__ catb)
{
    __shared__ __align__(16) ushort_t As2[16 * 512];
    __shared__ __align__(16) ushort_t Pt[128 * 64];
    const int t = threadIdx.x, i = blockIdx.x;
    const int w = t >> 6, l = t & 63;
    const int lr = l & 15, hk = l >> 4;

    // stage A_i from bf16 weights -> [16][512] swizzled (rows 12..15 zero)
    #pragma unroll
    for (int ii = 0; ii < 4; ++ii) {
        int idx = (t + ii * 256) * 8;
        int h = idx >> 9, j = idx & 511;
        bf16x8 v;
        if (h < 12) v = *(const bf16x8*)(attn_b + (size_t)h * NN + (size_t)i * 512 + j);
        else        v = (bf16x8){0,0,0,0,0,0,0,0};
        int byte = h * 1024 + ((j * 2) ^ ((h & 7) << 4));
        *(bf16x8*)((char*)As2 + byte) = v;
    }

    const float* psrc = p + (size_t)i * 65536;
    f32x4 pre[8];
    #pragma unroll
    for (int ii = 0; ii < 8; ++ii)
        pre[ii] = *(const f32x4*)(psrc + t * 4 + ii * 1024);

    f32x4 acc[2];
    acc[0] = (f32x4){0.f, 0.f, 0.f, 0.f};
    acc[1] = (f32x4){0.f, 0.f, 0.f, 0.f};

    __syncthreads();   // As2 ready

    for (int tile = 0; tile < 8; ++tile) {
        #pragma unroll
        for (int ii = 0; ii < 8; ++ii) {
            int idx = t * 4 + ii * 1024;
            int j = idx >> 7, c0 = idx & 127;
            #pragma unroll
            for (int e = 0; e < 4; ++e) {
                int c = c0 + e;
                int byte = c * 128 + ((j * 2) ^ ((((c >> 2) & 7)) << 4));
                *(ushort_t*)((char*)Pt + byte) = (ushort_t)f2bf(pre[ii][e]);
            }
        }
        if (tile < 7) {
            #pragma unroll
            for (int ii = 0; ii < 8; ++ii)
                pre[ii] = *(const f32x4*)(psrc + (tile + 1) * 8192 + t * 4 + ii * 1024);
        }
        __syncthreads();
        #pragma unroll
        for (int ks = 0; ks < 2; ++ks) {
            int kbyte = ks * 64 + hk * 16;
            bf16x8 afr = *(const bf16x8*)((char*)As2 + lr * 1024 +
                             ((tile * 128 + kbyte) ^ ((lr & 7) << 4)));
            #pragma unroll
            for (int n = 0; n < 2; ++n) {
                int c = w * 32 + n * 16 + lr;
                bf16x8 bfr = *(const bf16x8*)((char*)Pt + c * 128 +
                                 (kbyte ^ ((((c >> 2) & 7)) << 4)));
                acc[n] = __builtin_amdgcn_mfma_f32_16x16x32_bf16(afr, bfr, acc[n], 0, 0, 0);
            }
        }
        __syncthreads();
    }
    #pragma unroll
    for (int n = 0; n < 2; ++n) {
        int c = w * 32 + n * 16 + lr;
        #pragma unroll
        for (int r = 0; r < 4; ++r) {
            int h = hk * 4 + r;
            if (h < 12)
                catb[(size_t)i * DCAT + 576 + h * 128 + c] = (ushort_t)f2bf(acc[n][r]);
        }
    }
}

// ============ final: upd, quaternion, rot_new, trans_new ============
__global__ void final_kernel(const float* __restrict__ s2, const float* __restrict__ bb_w,
                             const float* __restrict__ bb_b, const float* __restrict__ rot,
                             const float* __restrict__ trans, float* __restrict__ out_rot,
                             float* __restrict__ out_trans)
{
    int i = blockIdx.x * 64 + threadIdx.x;
    if (i >= N) return;
    float u[6] = {0.f, 0.f, 0.f, 0.f, 0.f, 0.f};
    for (int k = 0; k < 384; ++k) {
        float sv = s2[(size_t)i * 384 + k];
        #pragma unroll
        for (int c = 0; c < 6; ++c) u[c] += sv * bb_w[k * 6 + c];
    }
    #pragma unroll
    for (int c = 0; c < 6; ++c) u[c] += bb_b[c];
    float inq = rsqrtf(1.0f + u[0] * u[0] + u[1] * u[1] + u[2] * u[2]);
    float w = inq, x = u[0] * inq, y = u[1] * inq, z = u[2] * inq;
    float Ru[9];
    Ru[0] = 1.f - 2.f * (y * y + z * z); Ru[1] = 2.f * (x * y - w * z); Ru[2] = 2.f * (x * z + w * y);
    Ru[3] = 2.f * (x * y + w * z); Ru[4] = 1.f - 2.f * (x * x + z * z); Ru[5] = 2.f * (y * z - w * x);
    Ru[6] = 2.f * (x * z - w * y); Ru[7] = 2.f * (y * z + w * x); Ru[8] = 1.f - 2.f * (x * x + y * y);
    const float* R = rot + i * 9;
    #pragma unroll
    for (int a = 0; a < 3; ++a) {
        #pragma unroll
        for (int cc = 0; cc < 3; ++cc)
            out_rot[i * 9 + a * 3 + cc] =
                R[a * 3 + 0] * Ru[0 + cc] + R[a * 3 + 1] * Ru[3 + cc] + R[a * 3 + 2] * Ru[6 + cc];
        out_trans[i * 3 + a] = R[a * 3 + 0] * u[3] + R[a * 3 + 1] * u[4] + R[a * 3 + 2] * u[5]
                               + trans[i * 3 + a];
    }
}

extern "C" void kernel_launch(void* const* d_in, const int* in_sizes, int n_in,
                              void* d_out, int out_size, void* d_ws, size_t ws_size,
                              hipStream_t stream)
{
    const float* s      = (const float*)d_in[0];
    const float* p      = (const float*)d_in[1];
    const float* rot    = (const float*)d_in[2];
    const float* trans  = (const float*)d_in[3];
    const float* mask   = (const float*)d_in[4];
    const float* w_q    = (const float*)d_in[5];
    const float* b_q    = (const float*)d_in[6];
    const float* w_kv   = (const float*)d_in[7];
    const float* b_kv   = (const float*)d_in[8];
    const float* w_qp   = (const float*)d_in[9];
    const float* b_qp   = (const float*)d_in[10];
    const float* w_kvp  = (const float*)d_in[11];
    const float* b_kvp  = (const float*)d_in[12];
    const float* w_b    = (const float*)d_in[13];
    const float* b_b    = (const float*)d_in[14];
    const float* head_w = (const float*)d_in[15];
    const float* w_o    = (const float*)d_in[16];
    const float* b_o    = (const float*)d_in[17];
    const float* ln1_g  = (const float*)d_in[18];
    const float* ln1_b  = (const float*)d_in[19];
    const float* tw1    = (const float*)d_in[20];
    const float* tb1    = (const float*)d_in[21];
    const float* tw2    = (const float*)d_in[22];
    const float* tb2    = (const float*)d_in[23];
    const float* tw3    = (const float*)d_in[24];
    const float* tb3    = (const float*)d_in[25];
    const float* ln2_g  = (const float*)d_in[26];
    const float* ln2_b  = (const float*)d_in[27];
    const float* bb_w   = (const float*)d_in[28];
    const float* bb_b   = (const float*)d_in[29];

    float* ws = (float*)d_ws;
    float*    wqkv  = ws;                        // 589824
    float*    parts = wqkv + 589824;             // 1179648
    float*    opr   = parts + 1179648;           // 147456
    float*    s1    = opr + 147456;              // 196608
    float*    biasp = s1 + 196608;               // 1152
    ushort_t* ub    = (ushort_t*)(biasp + 1152);
    ushort_t* bias_b = ub;                       // 3145728
    ushort_t* attn_b = bias_b + 3145728;         // 3145728
    ushort_t* catb   = attn_b + 3145728;         // 1081344
    ushort_t* sbf    = catb + 1081344;           // 196608
    ushort_t* s1bf   = sbf + 196608;
    ushort_t* h1bf   = s1bf + 196608;
    ushort_t* h2bf   = h1bf + 196608;
    ushort_t* Qext   = h2bf + 196608;            // 196608
    ushort_t* Kext   = Qext + 196608;            // 196608
    ushort_t* Vext   = Kext + 196608;            // 294912
    ushort_t* Wtp    = Vext + 294912;            // 442368
    ushort_t* Wto    = Wtp + 442368;             // 811008
    ushort_t* Wt1    = Wto + 811008;             // 147456
    ushort_t* Wt2    = Wt1 + 147456;
    ushort_t* Wt3    = Wt2 + 147456;

    float* out_s     = (float*)d_out;
    float* out_rot   = out_s + 196608;
    float* out_trans = out_rot + 4608;

    // ---- merged prep ----
    PrepArgs pa;
    pa.wsrc0 = w_q;  pa.wdst0 = Wtp;
    pa.wsrc1 = w_kv; pa.wdst1 = Wtp + (size_t)192 * 384;
    pa.wsrc2 = w_qp; pa.wdst2 = Wtp + (size_t)576 * 384;
    pa.wsrc3 = w_kvp; pa.wdst3 = Wtp + (size_t)720 * 384;
    pa.wsrc4 = w_o;  pa.wdst4 = Wto;
    pa.wsrc5 = tw1;  pa.wdst5 = Wt1;
    pa.wsrc6 = tw2;  pa.wdst6 = Wt2;
    pa.wsrc7 = tw3;  pa.wdst7 = Wt3;
    pa.s = s; pa.sbf = sbf;
    pa.bq = b_q; pa.bkv = b_kv; pa.bqp = b_qp; pa.bkvp = b_kvp;
    pa.biasp = biasp;
    prep_kernel<<<1861, 256, 0, stream>>>(pa);

    // ---- fused projection GEMM ----
    gemm_bf16<<<dim3(8, 18, 2), 256, 0, stream>>>(sbf, Wtp, parts, 384, 1152, 6);
    reduce_k<<<576, 256, 0, stream>>>(parts, 2, 1152, biasp, nullptr, 0, wqkv, nullptr);
    rotate_pts<<<96, 256, 0, stream>>>(wqkv, rot, trans, 576, 48);
    rotate_pts<<<288, 256, 0, stream>>>(wqkv, rot, trans, 720, 144);
    qkext_kernel<<<dim3(12, 4), 256, 0, stream>>>(wqkv, head_w, mask, Qext, Kext, Vext);

    // ---- attention ----
    bias_mfma<<<2048, 256, 0, stream>>>(p, w_b, b_b, bias_b);
    attn_mfma<<<dim3(16, 12), 256, 0, stream>>>(Qext, Kext, bias_b, attn_b);
    ov_mfma<<<dim3(32, 12), 64, 0, stream>>>(attn_b, Vext, catb, opr);
    opfin_kernel<<<192, 256, 0, stream>>>(opr, rot, trans, catb);
    opair_mfma<<<512, 256, 0, stream>>>(attn_b, p, catb);

    // ---- output projection + residual + LN1 ----
    gemm_bf16<<<dim3(8, 6, 6), 256, 0, stream>>>(catb, Wto, parts, 2112, 384, 11);
    reduce_ln<<<512, 128, 0, stream>>>(parts, 6, b_o, s, ln1_g, ln1_b, s1, s1bf);

    // ---- transition ----
    gemm_bf16<<<dim3(8, 6, 3), 256, 0, stream>>>(s1bf, Wt1, parts, 384, 384, 4);
    reduce_k<<<192, 256, 0, stream>>>(parts, 3, 384, tb1, nullptr, 1, nullptr, h1bf);
    gemm_bf16<<<dim3(8, 6, 3), 256, 0, stream>>>(h1bf, Wt2, parts, 384, 384, 4);
    reduce_k<<<192, 256, 0, stream>>>(parts, 3, 384, tb2, nullptr, 1, nullptr, h2bf);
    gemm_bf16<<<dim3(8, 6, 3), 256, 0, stream>>>(h2bf, Wt3, parts, 384, 384, 4);
    reduce_ln<<<512, 128, 0, stream>>>(parts, 3, tb3, s1, ln2_g, ln2_b, out_s, nullptr);

    // ---- rigid update ----
    final_kernel<<<8, 64, 0, stream>>>(out_s, bb_w, bb_b, rot, trans, out_rot, out_trans);
}